// Round 18
// baseline (189.675 us; speedup 1.0000x reference)
//
#include <hip/hip_runtime.h>
#include <hip/hip_bf16.h>

#define N_ENT   50000
#define N_EDGE  600000
#define FEAT    128
#define HID     256
#define OUT_D   128
#define MROWS   50048        // N_ENT padded to 64
#define BN_EPS  1e-5f
#define SCAN_BLKS 196        // ceil(N_ENT/256)
#define NT      (MROWS / 64) // 782 row-tiles of 64
#define NT2     (MROWS / 128)// 391 double-tiles
#define RED_BLKS 196         // ceil(NT/4)

// ---------------- ws layout (bytes) ----------------
#define OFF_DEGI    0               // [N_ENT] i32          200,000
#define OFF_SCALE   202048          // [HID] f32            1,024
#define OFF_SHIFT   203072          // [HID] f32            1,024
#define OFF_RELB    204096          // [101][128] bf16      25,856
#define OFF_WT1     229952          // fragment-major packed WmWsf^T  131,072
#define OFF_W1T     361024          // fragment-major packed W1^T     131,072
#define OFF_W2T     492096          // fragment-major packed W2^T     65,536
#define OFF_A       557632          // [MROWS][256] bf16 ([agg|x], linear)  25,624,576
#define OFF_Y       26182208        // [MROWS][256] bf16 (swizzled granules) 25,624,576
#define OFF_PB      52000000        // [NT][512] f32 partial (cs,cq interleaved) 1,601,536
#define OFF_PB2     53601536        // [196][512] f32 stage-2 partials 401,408
// CSR in its own region (r12 lesson: never overlay buffers whose lifetimes overlap)
#define OFF_ROWPTR  55000000        // [N_ENT+1] i32 200,064
#define OFF_FILLC   55200064        // [N_ENT] i32   200,000
#define OFF_PACKED  55400064        // [N_EDGE] i32  2,400,000
#define OFF_BSUM    57800064        // [196] i32
#define OFF_BOFF    57801088        // [196] i32

typedef __attribute__((ext_vector_type(8))) short bf16x8;
typedef __attribute__((ext_vector_type(4))) float f32x4;

#define GLL(gp, lp) __builtin_amdgcn_global_load_lds( \
    (const __attribute__((address_space(1))) void*)(gp), \
    (__attribute__((address_space(3))) void*)(lp), 16, 0, 0)

#define MFMA(a, b, c) __builtin_amdgcn_mfma_f32_16x16x32_bf16((a), (b), (c), 0, 0, 0)

__device__ __forceinline__ ushort f2bf(float f) {
    uint u = __float_as_uint(f);
    return (ushort)((u + 0x7FFFu + ((u >> 16) & 1u)) >> 16);
}
__device__ __forceinline__ float bflo(uint u) { return __uint_as_float(u << 16); }
__device__ __forceinline__ float bfhi(uint u) { return __uint_as_float(u & 0xFFFF0000u); }

// ---- prep (fused): cvt x->A right half | deg histogram | weight pack (fragment-major)
__global__ __launch_bounds__(256) void k_prep(
    const float* __restrict__ x, const int* __restrict__ ei,
    const float* __restrict__ Wm, const float* __restrict__ Wsf,
    const float* __restrict__ W1, const float* __restrict__ W2,
    const float* __restrict__ rel,
    ushort* __restrict__ A, int* __restrict__ degi,
    ushort* __restrict__ Wt1, ushort* __restrict__ W1t,
    ushort* __restrict__ W2t, ushort* __restrict__ relb)
{
    int b = blockIdx.x;
    if (b < 3125) {
        int idx = b * 256 + threadIdx.x;          // 800,000 exactly
        int m = idx >> 4;
        int c = (idx & 15) * 8;
        float4 f0 = *(const float4*)(x + m * FEAT + c);
        float4 f1 = *(const float4*)(x + m * FEAT + c + 4);
        uint4 o;
        o.x = (uint)f2bf(f0.x) | ((uint)f2bf(f0.y) << 16);
        o.y = (uint)f2bf(f0.z) | ((uint)f2bf(f0.w) << 16);
        o.z = (uint)f2bf(f1.x) | ((uint)f2bf(f1.y) << 16);
        o.w = (uint)f2bf(f1.z) | ((uint)f2bf(f1.w) << 16);
        *(uint4*)(A + m * 256 + FEAT + c) = o;
    } else if (b < 3125 + 2344) {
        int e = (b - 3125) * 256 + threadIdx.x;
        if (e < N_EDGE) atomicAdd(&degi[ei[N_EDGE + e]], 1);
    } else {
        int idx = (b - 5469) * 256 + threadIdx.x;
        if (idx < 65536) {                 // Wt1 pack
            int n = idx >> 8, k = idx & 255;
            float v = (k < FEAT) ? Wm[k * HID + n] : Wsf[(k - FEAT) * HID + n];
            int w = n >> 6, nb = (n >> 4) & 3, lr = n & 15;
            int kk = k >> 5, lk = (k >> 3) & 3, j = k & 7;
            int l = lk * 16 + lr;
            Wt1[(((w * 8 + kk) * 4 + nb) * 64 + l) * 8 + j] = f2bf(v);
        } else if (idx < 131072) {         // W1t pack
            int o = idx - 65536;
            int n = o >> 8, k = o & 255;
            float v = W1[k * HID + n];
            int w = n >> 6, nb = (n >> 4) & 3, lr = n & 15;
            int kk = k >> 5, lk = (k >> 3) & 3, j = k & 7;
            int l = lk * 16 + lr;
            W1t[(((w * 8 + kk) * 4 + nb) * 64 + l) * 8 + j] = f2bf(v);
        } else if (idx < 163840) {         // W2t pack
            int o = idx - 131072;
            int n = o >> 8, k = o & 255;
            float v = W2[k * OUT_D + n];
            int w = n >> 5, nb = (n >> 4) & 1, lr = n & 15;
            int kk = k >> 5, lk = (k >> 3) & 3, j = k & 7;
            int l = lk * 16 + lr;
            W2t[(((w * 8 + kk) * 2 + nb) * 64 + l) * 8 + j] = f2bf(v);
        } else if (idx < 163840 + 101 * 128) {
            int o = idx - 163840;
            relb[o] = f2bf(rel[o]);
        }
    }
}

// ---- scan pipeline
__global__ __launch_bounds__(256) void k_bsum(
    const int* __restrict__ degi, int* __restrict__ bsum)
{
    __shared__ int red[4];
    int idx = blockIdx.x * 256 + threadIdx.x;
    int v = (idx < N_ENT) ? degi[idx] : 0;
    #pragma unroll
    for (int off = 1; off < 64; off <<= 1) v += __shfl_xor(v, off);
    if ((threadIdx.x & 63) == 0) red[threadIdx.x >> 6] = v;
    __syncthreads();
    if (threadIdx.x == 0) bsum[blockIdx.x] = red[0] + red[1] + red[2] + red[3];
}

__global__ __launch_bounds__(256) void k_boff(
    const int* __restrict__ bsum, int* __restrict__ boff, int* __restrict__ rowptr)
{
    __shared__ int s[256];
    int t = threadIdx.x;
    int v = (t < SCAN_BLKS) ? bsum[t] : 0;
    s[t] = v;
    __syncthreads();
    for (int off = 1; off < 256; off <<= 1) {
        int u = (t >= off) ? s[t - off] : 0;
        __syncthreads();
        s[t] += u;
        __syncthreads();
    }
    if (t < SCAN_BLKS) boff[t] = s[t] - v;
    if (t == 255) rowptr[N_ENT] = s[255];
}

__global__ __launch_bounds__(256) void k_scan2(
    const int* __restrict__ degi, const int* __restrict__ boff,
    int* __restrict__ rowptr, int* __restrict__ fillc)
{
    __shared__ int s[256];
    int t = threadIdx.x;
    int idx = blockIdx.x * 256 + t;
    int v = (idx < N_ENT) ? degi[idx] : 0;
    s[t] = v;
    __syncthreads();
    for (int off = 1; off < 256; off <<= 1) {
        int u = (t >= off) ? s[t - off] : 0;
        __syncthreads();
        s[t] += u;
        __syncthreads();
    }
    if (idx < N_ENT) {
        int ex = s[t] - v + boff[blockIdx.x];
        rowptr[idx] = ex;
        fillc[idx]  = ex;
    }
}

__global__ __launch_bounds__(256) void k_fill(
    const int* __restrict__ ei, const int* __restrict__ et,
    int* __restrict__ fillc, int* __restrict__ packed)
{
    int e = blockIdx.x * 256 + threadIdx.x;
    if (e >= N_EDGE) return;
    int dst = ei[N_EDGE + e];
    int pos = atomicAdd(&fillc[dst], 1);
    packed[pos] = ei[e] | (et[e] << 16);
}

// ---- agg: segment mean, one node/wave; 8/4/2/1 MLP ladder
__global__ __launch_bounds__(256) void k_agg(
    const int* __restrict__ rowptr, const int* __restrict__ packed,
    ushort* __restrict__ A, const ushort* __restrict__ relb)
{
    int node = blockIdx.x * 4 + (threadIdx.x >> 6);
    int lane = threadIdx.x & 63;
    int e0 = rowptr[node], e1 = rowptr[node + 1];
    float ax = 0.f, ay = 0.f;
    int e = e0;
    for (; e + 8 <= e1; e += 8) {
        int p0 = packed[e],     p1 = packed[e + 1], p2 = packed[e + 2], p3 = packed[e + 3];
        int p4 = packed[e + 4], p5 = packed[e + 5], p6 = packed[e + 6], p7 = packed[e + 7];
        uint xv0 = *(const uint*)(A + (p0 & 0xFFFF) * 256 + FEAT + lane * 2);
        uint rv0 = *(const uint*)(relb + (p0 >> 16) * FEAT + lane * 2);
        uint xv1 = *(const uint*)(A + (p1 & 0xFFFF) * 256 + FEAT + lane * 2);
        uint rv1 = *(const uint*)(relb + (p1 >> 16) * FEAT + lane * 2);
        uint xv2 = *(const uint*)(A + (p2 & 0xFFFF) * 256 + FEAT + lane * 2);
        uint rv2 = *(const uint*)(relb + (p2 >> 16) * FEAT + lane * 2);
        uint xv3 = *(const uint*)(A + (p3 & 0xFFFF) * 256 + FEAT + lane * 2);
        uint rv3 = *(const uint*)(relb + (p3 >> 16) * FEAT + lane * 2);
        uint xv4 = *(const uint*)(A + (p4 & 0xFFFF) * 256 + FEAT + lane * 2);
        uint rv4 = *(const uint*)(relb + (p4 >> 16) * FEAT + lane * 2);
        uint xv5 = *(const uint*)(A + (p5 & 0xFFFF) * 256 + FEAT + lane * 2);
        uint rv5 = *(const uint*)(relb + (p5 >> 16) * FEAT + lane * 2);
        uint xv6 = *(const uint*)(A + (p6 & 0xFFFF) * 256 + FEAT + lane * 2);
        uint rv6 = *(const uint*)(relb + (p6 >> 16) * FEAT + lane * 2);
        uint xv7 = *(const uint*)(A + (p7 & 0xFFFF) * 256 + FEAT + lane * 2);
        uint rv7 = *(const uint*)(relb + (p7 >> 16) * FEAT + lane * 2);
        ax += bflo(xv0) + bflo(rv0) + bflo(xv1) + bflo(rv1)
            + bflo(xv2) + bflo(rv2) + bflo(xv3) + bflo(rv3)
            + bflo(xv4) + bflo(rv4) + bflo(xv5) + bflo(rv5)
            + bflo(xv6) + bflo(rv6) + bflo(xv7) + bflo(rv7);
        ay += bfhi(xv0) + bfhi(rv0) + bfhi(xv1) + bfhi(rv1)
            + bfhi(xv2) + bfhi(rv2) + bfhi(xv3) + bfhi(rv3)
            + bfhi(xv4) + bfhi(rv4) + bfhi(xv5) + bfhi(rv5)
            + bfhi(xv6) + bfhi(rv6) + bfhi(xv7) + bfhi(rv7);
    }
    for (; e + 4 <= e1; e += 4) {
        int p0 = packed[e], p1 = packed[e + 1], p2 = packed[e + 2], p3 = packed[e + 3];
        uint xv0 = *(const uint*)(A + (p0 & 0xFFFF) * 256 + FEAT + lane * 2);
        uint rv0 = *(const uint*)(relb + (p0 >> 16) * FEAT + lane * 2);
        uint xv1 = *(const uint*)(A + (p1 & 0xFFFF) * 256 + FEAT + lane * 2);
        uint rv1 = *(const uint*)(relb + (p1 >> 16) * FEAT + lane * 2);
        uint xv2 = *(const uint*)(A + (p2 & 0xFFFF) * 256 + FEAT + lane * 2);
        uint rv2 = *(const uint*)(relb + (p2 >> 16) * FEAT + lane * 2);
        uint xv3 = *(const uint*)(A + (p3 & 0xFFFF) * 256 + FEAT + lane * 2);
        uint rv3 = *(const uint*)(relb + (p3 >> 16) * FEAT + lane * 2);
        ax += bflo(xv0) + bflo(rv0) + bflo(xv1) + bflo(rv1)
            + bflo(xv2) + bflo(rv2) + bflo(xv3) + bflo(rv3);
        ay += bfhi(xv0) + bfhi(rv0) + bfhi(xv1) + bfhi(rv1)
            + bfhi(xv2) + bfhi(rv2) + bfhi(xv3) + bfhi(rv3);
    }
    for (; e + 2 <= e1; e += 2) {
        int p0 = packed[e], p1 = packed[e + 1];
        uint xv0 = *(const uint*)(A + (p0 & 0xFFFF) * 256 + FEAT + lane * 2);
        uint rv0 = *(const uint*)(relb + (p0 >> 16) * FEAT + lane * 2);
        uint xv1 = *(const uint*)(A + (p1 & 0xFFFF) * 256 + FEAT + lane * 2);
        uint rv1 = *(const uint*)(relb + (p1 >> 16) * FEAT + lane * 2);
        ax += bflo(xv0) + bflo(rv0) + bflo(xv1) + bflo(rv1);
        ay += bfhi(xv0) + bfhi(rv0) + bfhi(xv1) + bfhi(rv1);
    }
    if (e < e1) {
        int p = packed[e];
        uint xv = *(const uint*)(A + (p & 0xFFFF) * 256 + FEAT + lane * 2);
        uint rv = *(const uint*)(relb + (p >> 16) * FEAT + lane * 2);
        ax += bflo(xv) + bflo(rv);
        ay += bfhi(xv) + bfhi(rv);
    }
    float invd = 1.0f / fmaxf((float)(e1 - e0), 1.0f);
    uint o = (uint)f2bf(ax * invd) | ((uint)f2bf(ay * invd) << 16);
    *(uint*)(A + node * 256 + lane * 2) = o;
}

// ---- hy: 2 tiles/block, both A-tiles staged up-front (one vmcnt drain);
// tile0's y-stores overlap tile1's compute. 64KB LDS -> 2 blocks/CU.
__global__ __launch_bounds__(256) void k_hy(
    const ushort* __restrict__ A, const ushort* __restrict__ Wt1,
    const ushort* __restrict__ W1t,
    const float* __restrict__ bm, const float* __restrict__ b1,
    ushort* __restrict__ y, float* __restrict__ pb)
{
    __shared__ ushort a_s[2][64 * 256];   // 64 KB
    int tid = threadIdx.x;
    int w = tid >> 6, l = tid & 63;
    int lr = l & 15, lk = l >> 4;

    // stage BOTH tiles
    {
        const ushort* srcb = A + (size_t)blockIdx.x * 128 * 256;
        #pragma unroll
        for (int tt = 0; tt < 2; ++tt)
            #pragma unroll
            for (int j = 0; j < 8; ++j) {
                int slot = (w * 8 + j) * 64 + l;
                int lrow = slot >> 5, lgr = slot & 31;
                GLL(srcb + (tt * 64 + lrow) * 256 + ((lgr ^ (lrow & 7)) << 3),
                    &a_s[tt][(w * 8 + j) * 512]);
            }
    }
    __syncthreads();

    #pragma unroll
    for (int tt = 0; tt < 2; ++tt) {
        int tile = blockIdx.x * 2 + tt;
        int m0 = tile * 64;
        ushort* as = a_s[tt];

        // ---- phase 1: h = [agg|x] @ [Wm;Wsf] (+bm)
        f32x4 acc[4][4] = {};
        const ushort* Bp = Wt1 + w * 16384 + l * 8;
        #pragma unroll
        for (int kk = 0; kk < 8; ++kk) {
            bf16x8 a[4], b[4];
            #pragma unroll
            for (int mb = 0; mb < 4; ++mb) {
                int row = mb * 16 + lr;
                a[mb] = *(const bf16x8*)&as[row * 256 + (((kk * 4 + lk) ^ (lr & 7)) << 3)];
            }
            #pragma unroll
            for (int nb = 0; nb < 4; ++nb) b[nb] = *(const bf16x8*)(Bp + kk * 2048 + nb * 512);
            #pragma unroll
            for (int mb = 0; mb < 4; ++mb)
                #pragma unroll
                for (int nb = 0; nb < 4; ++nb)
                    acc[mb][nb] = MFMA(a[mb], b[nb], acc[mb][nb]);
        }
        __syncthreads();   // as reads done; reuse for h

        #pragma unroll
        for (int nb = 0; nb < 4; ++nb) {
            int col = w * 64 + nb * 16 + lr;
            float bias = bm[col];
            #pragma unroll
            for (int mb = 0; mb < 4; ++mb)
                #pragma unroll
                for (int r = 0; r < 4; ++r) {
                    int row = mb * 16 + lk * 4 + r;
                    as[row * 256 + (col ^ ((row & 7) << 3))] = f2bf(acc[mb][nb][r] + bias);
                }
        }
        __syncthreads();

        // ---- phase 2: y = h @ W1 (+b1)
        f32x4 acc2[4][4] = {};
        const ushort* B2p = W1t + w * 16384 + l * 8;
        #pragma unroll
        for (int kk = 0; kk < 8; ++kk) {
            bf16x8 a[4], b[4];
            #pragma unroll
            for (int mb = 0; mb < 4; ++mb) {
                int row = mb * 16 + lr;
                a[mb] = *(const bf16x8*)&as[row * 256 + ((kk * 32 + lk * 8) ^ ((row & 7) << 3))];
            }
            #pragma unroll
            for (int nb = 0; nb < 4; ++nb) b[nb] = *(const bf16x8*)(B2p + kk * 2048 + nb * 512);
            #pragma unroll
            for (int mb = 0; mb < 4; ++mb)
                #pragma unroll
                for (int nb = 0; nb < 4; ++nb)
                    acc2[mb][nb] = MFMA(a[mb], b[nb], acc2[mb][nb]);
        }
        __syncthreads();   // h reads done; reuse as for y staging

        #pragma unroll
        for (int nb = 0; nb < 4; ++nb) {
            int col = w * 64 + nb * 16 + lr;
            float b1v = b1[col];
            float cs = 0.f, cq = 0.f;
            #pragma unroll
            for (int mb = 0; mb < 4; ++mb)
                #pragma unroll
                for (int r = 0; r < 4; ++r) {
                    int row = mb * 16 + lk * 4 + r;
                    float v = acc2[mb][nb][r] + b1v;
                    if (m0 + row < N_ENT) { cs += v; cq += v * v; }
                    as[row * 256 + (col ^ ((row & 7) << 3))] = f2bf(v);
                }
            cs += __shfl_xor(cs, 16); cs += __shfl_xor(cs, 32);
            cq += __shfl_xor(cq, 16); cq += __shfl_xor(cq, 32);
            if (lk == 0) {
                *(float2*)(pb + (size_t)tile * 512 + col * 2) = make_float2(cs, cq);
            }
        }
        __syncthreads();
        ushort* yp = y + (size_t)m0 * 256;
        #pragma unroll
        for (int i = 0; i < 8; ++i) {
            int off = i * 2048 + tid * 8;
            *(uint4*)(yp + off) = *(const uint4*)&as[off];
        }
        // no barrier: next tt uses the other buffer; stores drain in background
    }
}

// ---- red1: parallel stage-1 reduce: 196 blocks x 4 tiles -> pb2[196][512]
__global__ __launch_bounds__(256) void k_red1(
    const float* __restrict__ pb, float* __restrict__ pb2)
{
    int b = blockIdx.x, tid = threadIdx.x;
    int t0 = b * 4;
    float sx = 0.f, sy = 0.f;
    #pragma unroll
    for (int i = 0; i < 4; ++i) {
        int t = t0 + i;
        if (t < NT) {
            float2 v = *(const float2*)(pb + (size_t)t * 512 + tid * 2);
            sx += v.x; sy += v.y;
        }
    }
    *(float2*)(pb2 + (size_t)b * 512 + tid * 2) = make_float2(sx, sy);
}

// ---- red2: stage-2 reduce + BN finalize
__global__ __launch_bounds__(256) void k_red2(
    const float* __restrict__ pb2,
    const float* __restrict__ gamma, const float* __restrict__ beta,
    float* __restrict__ scale, float* __restrict__ shift)
{
    int c = threadIdx.x;
    float s = 0.f, q = 0.f;
    int b = 0;
    #pragma unroll
    for (; b + 8 <= RED_BLKS; b += 8) {
        float2 v0 = *(const float2*)(pb2 + (size_t)(b + 0) * 512 + c * 2);
        float2 v1 = *(const float2*)(pb2 + (size_t)(b + 1) * 512 + c * 2);
        float2 v2 = *(const float2*)(pb2 + (size_t)(b + 2) * 512 + c * 2);
        float2 v3 = *(const float2*)(pb2 + (size_t)(b + 3) * 512 + c * 2);
        float2 v4 = *(const float2*)(pb2 + (size_t)(b + 4) * 512 + c * 2);
        float2 v5 = *(const float2*)(pb2 + (size_t)(b + 5) * 512 + c * 2);
        float2 v6 = *(const float2*)(pb2 + (size_t)(b + 6) * 512 + c * 2);
        float2 v7 = *(const float2*)(pb2 + (size_t)(b + 7) * 512 + c * 2);
        s += v0.x + v1.x + v2.x + v3.x + v4.x + v5.x + v6.x + v7.x;
        q += v0.y + v1.y + v2.y + v3.y + v4.y + v5.y + v6.y + v7.y;
    }
    for (; b < RED_BLKS; ++b) {
        float2 v = *(const float2*)(pb2 + (size_t)b * 512 + c * 2);
        s += v.x; q += v.y;
    }
    const float invn = 1.0f / (float)N_ENT;
    float mean = s * invn;
    float var  = q * invn - mean * mean;
    float rstd = rsqrtf(var + BN_EPS);
    float sc   = gamma[c] * rstd;
    scale[c] = sc;
    shift[c] = beta[c] - mean * sc;
}

// ---- zout: 2 tiles/block, both y-tiles staged up-front; out0 stores overlap tile1.
__global__ __launch_bounds__(256) void k_zout(
    const ushort* __restrict__ y, const float* __restrict__ scale,
    const float* __restrict__ shift, const ushort* __restrict__ W2t,
    const float* __restrict__ b2, float* __restrict__ out)
{
    __shared__ ushort z_s[2][64 * 256];   // 64 KB
    int tid = threadIdx.x;
    int w = tid >> 6, l = tid & 63;
    int lr = l & 15, lk = l >> 4;

    {
        const ushort* srcb = y + (size_t)blockIdx.x * 128 * 256;
        #pragma unroll
        for (int tt = 0; tt < 2; ++tt)
            #pragma unroll
            for (int j = 0; j < 8; ++j)
                GLL(srcb + (size_t)tt * 64 * 256 + ((w * 8 + j) * 64 + l) * 8,
                    &z_s[tt][(w * 8 + j) * 512]);
    }
    __syncthreads();

    #pragma unroll
    for (int tt = 0; tt < 2; ++tt) {
        int m0 = (blockIdx.x * 2 + tt) * 64;
        const ushort* zs = z_s[tt];

        f32x4 acc[4][2] = {};
        const ushort* Bp = W2t + w * 8192 + l * 8;
        #pragma unroll
        for (int kk = 0; kk < 8; ++kk) {
            int kb = kk * 32 + lk * 8;
            float scv[8], shv[8];
            *(float4*)&scv[0] = *(const float4*)(scale + kb);
            *(float4*)&scv[4] = *(const float4*)(scale + kb + 4);
            *(float4*)&shv[0] = *(const float4*)(shift + kb);
            *(float4*)&shv[4] = *(const float4*)(shift + kb + 4);
            bf16x8 b[2];
            #pragma unroll
            for (int nb = 0; nb < 2; ++nb) b[nb] = *(const bf16x8*)(Bp + kk * 1024 + nb * 512);
            bf16x8 a[4];
            #pragma unroll
            for (int mb = 0; mb < 4; ++mb) {
                int row = mb * 16 + lr;
                uint4 uv = *(const uint4*)&zs[row * 256 + (kb ^ ((row & 7) << 3))];
                uint wd[4] = {uv.x, uv.y, uv.z, uv.w};
                #pragma unroll
                for (int j = 0; j < 8; ++j) {
                    uint bits = (j & 1) ? (wd[j >> 1] & 0xFFFF0000u) : (wd[j >> 1] << 16);
                    float f = __uint_as_float(bits);
                    float z = fmaxf(f * scv[j] + shv[j], 0.f);
                    a[mb][j] = (short)f2bf(z);
                }
            }
            #pragma unroll
            for (int mb = 0; mb < 4; ++mb)
                #pragma unroll
                for (int nb = 0; nb < 2; ++nb)
                    acc[mb][nb] = MFMA(a[mb], b[nb], acc[mb][nb]);
        }
        #pragma unroll
        for (int nb = 0; nb < 2; ++nb) {
            int col = w * 32 + nb * 16 + lr;
            float b2v = b2[col];
            #pragma unroll
            for (int mb = 0; mb < 4; ++mb)
                #pragma unroll
                for (int r = 0; r < 4; ++r) {
                    int row = m0 + mb * 16 + lk * 4 + r;
                    if (row < N_ENT) out[row * OUT_D + col] = acc[mb][nb][r] + b2v;
                }
        }
    }
}

extern "C" void kernel_launch(void* const* d_in, const int* in_sizes, int n_in,
                              void* d_out, int out_size, void* d_ws, size_t ws_size,
                              hipStream_t stream)
{
    const int*   ei    = (const int*)d_in[0];
    const int*   et    = (const int*)d_in[1];
    const float* x     = (const float*)d_in[2];
    const float* rel   = (const float*)d_in[3];
    const float* Wm    = (const float*)d_in[4];
    const float* bm    = (const float*)d_in[5];
    const float* Wsf   = (const float*)d_in[6];
    const float* W1    = (const float*)d_in[7];
    const float* b1    = (const float*)d_in[8];
    const float* gamma = (const float*)d_in[9];
    const float* beta  = (const float*)d_in[10];
    const float* W2    = (const float*)d_in[11];
    const float* b2    = (const float*)d_in[12];
    float* out = (float*)d_out;

    char* ws = (char*)d_ws;
    int*    degi   = (int*)(ws + OFF_DEGI);
    float*  scale  = (float*)(ws + OFF_SCALE);
    float*  shift  = (float*)(ws + OFF_SHIFT);
    ushort* relb   = (ushort*)(ws + OFF_RELB);
    ushort* Wt1    = (ushort*)(ws + OFF_WT1);
    ushort* W1t    = (ushort*)(ws + OFF_W1T);
    ushort* W2t    = (ushort*)(ws + OFF_W2T);
    ushort* A      = (ushort*)(ws + OFF_A);
    ushort* y      = (ushort*)(ws + OFF_Y);
    int*    rowptr = (int*)(ws + OFF_ROWPTR);
    int*    fillc  = (int*)(ws + OFF_FILLC);
    int*    packed = (int*)(ws + OFF_PACKED);
    int*    bsum   = (int*)(ws + OFF_BSUM);
    int*    boff   = (int*)(ws + OFF_BOFF);
    float*  pb     = (float*)(ws + OFF_PB);
    float*  pb2    = (float*)(ws + OFF_PB2);

    // pad rows 50000..50047 of A are never written: they only feed row-guarded
    // outputs (stats + out both check row < N_ENT), so no pad memset needed.
    hipMemsetAsync(ws + OFF_DEGI, 0, 200000, stream);

    k_prep <<<6160, 256, 0, stream>>>(x, ei, Wm, Wsf, W1, W2, rel, A, degi, Wt1, W1t, W2t, relb);
    k_bsum <<<SCAN_BLKS, 256, 0, stream>>>(degi, bsum);
    k_boff <<<1, 256, 0, stream>>>(bsum, boff, rowptr);
    k_scan2<<<SCAN_BLKS, 256, 0, stream>>>(degi, boff, rowptr, fillc);
    k_fill <<<(N_EDGE + 255) / 256, 256, 0, stream>>>(ei, et, fillc, packed);
    k_agg  <<<N_ENT / 4, 256, 0, stream>>>(rowptr, packed, A, relb);
    k_hy   <<<NT2, 256, 0, stream>>>(A, Wt1, W1t, bm, b1, y, pb);
    k_red1 <<<RED_BLKS, 256, 0, stream>>>(pb, pb2);
    k_red2 <<<1, 256, 0, stream>>>(pb2, gamma, beta, scale, shift);
    k_zout <<<NT2, 256, 0, stream>>>(y, scale, shift, W2t, b2, out);
}

// Round 19
// 176.850 us; speedup vs baseline: 1.0725x; 1.0725x over previous
//
#include <hip/hip_runtime.h>
#include <hip/hip_bf16.h>

#define N_ENT   50000
#define N_EDGE  600000
#define FEAT    128
#define HID     256
#define OUT_D   128
#define MROWS   50048        // N_ENT padded to 64
#define BN_EPS  1e-5f
#define SCAN_BLKS 196        // ceil(N_ENT/256)
#define NT32    (MROWS / 32) // 1564 row-tiles of 32 (k_hy)
#define NT64    (MROWS / 64) // 782 row-tiles of 64 (k_zout)
#define RED_BLKS 196         // ceil(NT32/8)

// ---------------- ws layout (bytes) ----------------
#define OFF_DEGI    0               // [N_ENT] i32          200,000
#define OFF_SCALE   202048          // [HID] f32            1,024
#define OFF_SHIFT   203072          // [HID] f32            1,024
#define OFF_RELB    204096          // [101][128] bf16      25,856
#define OFF_WT1     229952          // fragment-major packed WmWsf^T  131,072
#define OFF_W1T     361024          // fragment-major packed W1^T     131,072
#define OFF_W2T     492096          // fragment-major packed W2^T     65,536
#define OFF_A       557632          // [MROWS][256] bf16 ([agg|x], linear)  25,624,576
#define OFF_Y       26182208        // [MROWS][256] bf16 (swizzled granules) 25,624,576
#define OFF_PB      52000000        // [NT32][512] f32 partials 3,203,072 -> ends 55,203,072
#define OFF_PB2     55210000        // [196][512] f32 stage-2 partials 401,408
// CSR in its own region (r12 lesson)
#define OFF_ROWPTR  56000000        // [N_ENT+1] i32 200,064
#define OFF_FILLC   56200064        // [N_ENT] i32   200,000
#define OFF_PACKED  56400064        // [N_EDGE] i32  2,400,000
#define OFF_BSUM    58800064        // [196] i32
#define OFF_BOFF    58801088        // [196] i32

typedef __attribute__((ext_vector_type(8))) short bf16x8;
typedef __attribute__((ext_vector_type(4))) float f32x4;

#define GLL(gp, lp) __builtin_amdgcn_global_load_lds( \
    (const __attribute__((address_space(1))) void*)(gp), \
    (__attribute__((address_space(3))) void*)(lp), 16, 0, 0)

#define MFMA(a, b, c) __builtin_amdgcn_mfma_f32_16x16x32_bf16((a), (b), (c), 0, 0, 0)

__device__ __forceinline__ ushort f2bf(float f) {
    uint u = __float_as_uint(f);
    return (ushort)((u + 0x7FFFu + ((u >> 16) & 1u)) >> 16);
}
__device__ __forceinline__ float bflo(uint u) { return __uint_as_float(u << 16); }
__device__ __forceinline__ float bfhi(uint u) { return __uint_as_float(u & 0xFFFF0000u); }

// ---- prep (fused): cvt x->A right half | deg histogram | weight pack (fragment-major)
__global__ __launch_bounds__(256) void k_prep(
    const float* __restrict__ x, const int* __restrict__ ei,
    const float* __restrict__ Wm, const float* __restrict__ Wsf,
    const float* __restrict__ W1, const float* __restrict__ W2,
    const float* __restrict__ rel,
    ushort* __restrict__ A, int* __restrict__ degi,
    ushort* __restrict__ Wt1, ushort* __restrict__ W1t,
    ushort* __restrict__ W2t, ushort* __restrict__ relb)
{
    int b = blockIdx.x;
    if (b < 3125) {
        int idx = b * 256 + threadIdx.x;          // 800,000 exactly
        int m = idx >> 4;
        int c = (idx & 15) * 8;
        float4 f0 = *(const float4*)(x + m * FEAT + c);
        float4 f1 = *(const float4*)(x + m * FEAT + c + 4);
        uint4 o;
        o.x = (uint)f2bf(f0.x) | ((uint)f2bf(f0.y) << 16);
        o.y = (uint)f2bf(f0.z) | ((uint)f2bf(f0.w) << 16);
        o.z = (uint)f2bf(f1.x) | ((uint)f2bf(f1.y) << 16);
        o.w = (uint)f2bf(f1.z) | ((uint)f2bf(f1.w) << 16);
        *(uint4*)(A + m * 256 + FEAT + c) = o;
    } else if (b < 3125 + 2344) {
        int e = (b - 3125) * 256 + threadIdx.x;
        if (e < N_EDGE) atomicAdd(&degi[ei[N_EDGE + e]], 1);
    } else {
        int idx = (b - 5469) * 256 + threadIdx.x;
        if (idx < 65536) {                 // Wt1 pack
            int n = idx >> 8, k = idx & 255;
            float v = (k < FEAT) ? Wm[k * HID + n] : Wsf[(k - FEAT) * HID + n];
            int w = n >> 6, nb = (n >> 4) & 3, lr = n & 15;
            int kk = k >> 5, lk = (k >> 3) & 3, j = k & 7;
            int l = lk * 16 + lr;
            Wt1[(((w * 8 + kk) * 4 + nb) * 64 + l) * 8 + j] = f2bf(v);
        } else if (idx < 131072) {         // W1t pack
            int o = idx - 65536;
            int n = o >> 8, k = o & 255;
            float v = W1[k * HID + n];
            int w = n >> 6, nb = (n >> 4) & 3, lr = n & 15;
            int kk = k >> 5, lk = (k >> 3) & 3, j = k & 7;
            int l = lk * 16 + lr;
            W1t[(((w * 8 + kk) * 4 + nb) * 64 + l) * 8 + j] = f2bf(v);
        } else if (idx < 163840) {         // W2t pack
            int o = idx - 131072;
            int n = o >> 8, k = o & 255;
            float v = W2[k * OUT_D + n];
            int w = n >> 5, nb = (n >> 4) & 1, lr = n & 15;
            int kk = k >> 5, lk = (k >> 3) & 3, j = k & 7;
            int l = lk * 16 + lr;
            W2t[(((w * 8 + kk) * 2 + nb) * 64 + l) * 8 + j] = f2bf(v);
        } else if (idx < 163840 + 101 * 128) {
            int o = idx - 163840;
            relb[o] = f2bf(rel[o]);
        }
    }
}

// ---- scan pipeline
__global__ __launch_bounds__(256) void k_bsum(
    const int* __restrict__ degi, int* __restrict__ bsum)
{
    __shared__ int red[4];
    int idx = blockIdx.x * 256 + threadIdx.x;
    int v = (idx < N_ENT) ? degi[idx] : 0;
    #pragma unroll
    for (int off = 1; off < 64; off <<= 1) v += __shfl_xor(v, off);
    if ((threadIdx.x & 63) == 0) red[threadIdx.x >> 6] = v;
    __syncthreads();
    if (threadIdx.x == 0) bsum[blockIdx.x] = red[0] + red[1] + red[2] + red[3];
}

__global__ __launch_bounds__(256) void k_boff(
    const int* __restrict__ bsum, int* __restrict__ boff, int* __restrict__ rowptr)
{
    __shared__ int s[256];
    int t = threadIdx.x;
    int v = (t < SCAN_BLKS) ? bsum[t] : 0;
    s[t] = v;
    __syncthreads();
    for (int off = 1; off < 256; off <<= 1) {
        int u = (t >= off) ? s[t - off] : 0;
        __syncthreads();
        s[t] += u;
        __syncthreads();
    }
    if (t < SCAN_BLKS) boff[t] = s[t] - v;
    if (t == 255) rowptr[N_ENT] = s[255];
}

__global__ __launch_bounds__(256) void k_scan2(
    const int* __restrict__ degi, const int* __restrict__ boff,
    int* __restrict__ rowptr, int* __restrict__ fillc)
{
    __shared__ int s[256];
    int t = threadIdx.x;
    int idx = blockIdx.x * 256 + t;
    int v = (idx < N_ENT) ? degi[idx] : 0;
    s[t] = v;
    __syncthreads();
    for (int off = 1; off < 256; off <<= 1) {
        int u = (t >= off) ? s[t - off] : 0;
        __syncthreads();
        s[t] += u;
        __syncthreads();
    }
    if (idx < N_ENT) {
        int ex = s[t] - v + boff[blockIdx.x];
        rowptr[idx] = ex;
        fillc[idx]  = ex;
    }
}

__global__ __launch_bounds__(256) void k_fill(
    const int* __restrict__ ei, const int* __restrict__ et,
    int* __restrict__ fillc, int* __restrict__ packed)
{
    int e = blockIdx.x * 256 + threadIdx.x;
    if (e >= N_EDGE) return;
    int dst = ei[N_EDGE + e];
    int pos = atomicAdd(&fillc[dst], 1);
    packed[pos] = ei[e] | (et[e] << 16);
}

// ---- agg: segment mean, one node/wave; 8/4/2/1 MLP ladder
__global__ __launch_bounds__(256) void k_agg(
    const int* __restrict__ rowptr, const int* __restrict__ packed,
    ushort* __restrict__ A, const ushort* __restrict__ relb)
{
    int node = blockIdx.x * 4 + (threadIdx.x >> 6);
    int lane = threadIdx.x & 63;
    int e0 = rowptr[node], e1 = rowptr[node + 1];
    float ax = 0.f, ay = 0.f;
    int e = e0;
    for (; e + 8 <= e1; e += 8) {
        int p0 = packed[e],     p1 = packed[e + 1], p2 = packed[e + 2], p3 = packed[e + 3];
        int p4 = packed[e + 4], p5 = packed[e + 5], p6 = packed[e + 6], p7 = packed[e + 7];
        uint xv0 = *(const uint*)(A + (p0 & 0xFFFF) * 256 + FEAT + lane * 2);
        uint rv0 = *(const uint*)(relb + (p0 >> 16) * FEAT + lane * 2);
        uint xv1 = *(const uint*)(A + (p1 & 0xFFFF) * 256 + FEAT + lane * 2);
        uint rv1 = *(const uint*)(relb + (p1 >> 16) * FEAT + lane * 2);
        uint xv2 = *(const uint*)(A + (p2 & 0xFFFF) * 256 + FEAT + lane * 2);
        uint rv2 = *(const uint*)(relb + (p2 >> 16) * FEAT + lane * 2);
        uint xv3 = *(const uint*)(A + (p3 & 0xFFFF) * 256 + FEAT + lane * 2);
        uint rv3 = *(const uint*)(relb + (p3 >> 16) * FEAT + lane * 2);
        uint xv4 = *(const uint*)(A + (p4 & 0xFFFF) * 256 + FEAT + lane * 2);
        uint rv4 = *(const uint*)(relb + (p4 >> 16) * FEAT + lane * 2);
        uint xv5 = *(const uint*)(A + (p5 & 0xFFFF) * 256 + FEAT + lane * 2);
        uint rv5 = *(const uint*)(relb + (p5 >> 16) * FEAT + lane * 2);
        uint xv6 = *(const uint*)(A + (p6 & 0xFFFF) * 256 + FEAT + lane * 2);
        uint rv6 = *(const uint*)(relb + (p6 >> 16) * FEAT + lane * 2);
        uint xv7 = *(const uint*)(A + (p7 & 0xFFFF) * 256 + FEAT + lane * 2);
        uint rv7 = *(const uint*)(relb + (p7 >> 16) * FEAT + lane * 2);
        ax += bflo(xv0) + bflo(rv0) + bflo(xv1) + bflo(rv1)
            + bflo(xv2) + bflo(rv2) + bflo(xv3) + bflo(rv3)
            + bflo(xv4) + bflo(rv4) + bflo(xv5) + bflo(rv5)
            + bflo(xv6) + bflo(rv6) + bflo(xv7) + bflo(rv7);
        ay += bfhi(xv0) + bfhi(rv0) + bfhi(xv1) + bfhi(rv1)
            + bfhi(xv2) + bfhi(rv2) + bfhi(xv3) + bfhi(rv3)
            + bfhi(xv4) + bfhi(rv4) + bfhi(xv5) + bfhi(rv5)
            + bfhi(xv6) + bfhi(rv6) + bfhi(xv7) + bfhi(rv7);
    }
    for (; e + 4 <= e1; e += 4) {
        int p0 = packed[e], p1 = packed[e + 1], p2 = packed[e + 2], p3 = packed[e + 3];
        uint xv0 = *(const uint*)(A + (p0 & 0xFFFF) * 256 + FEAT + lane * 2);
        uint rv0 = *(const uint*)(relb + (p0 >> 16) * FEAT + lane * 2);
        uint xv1 = *(const uint*)(A + (p1 & 0xFFFF) * 256 + FEAT + lane * 2);
        uint rv1 = *(const uint*)(relb + (p1 >> 16) * FEAT + lane * 2);
        uint xv2 = *(const uint*)(A + (p2 & 0xFFFF) * 256 + FEAT + lane * 2);
        uint rv2 = *(const uint*)(relb + (p2 >> 16) * FEAT + lane * 2);
        uint xv3 = *(const uint*)(A + (p3 & 0xFFFF) * 256 + FEAT + lane * 2);
        uint rv3 = *(const uint*)(relb + (p3 >> 16) * FEAT + lane * 2);
        ax += bflo(xv0) + bflo(rv0) + bflo(xv1) + bflo(rv1)
            + bflo(xv2) + bflo(rv2) + bflo(xv3) + bflo(rv3);
        ay += bfhi(xv0) + bfhi(rv0) + bfhi(xv1) + bfhi(rv1)
            + bfhi(xv2) + bfhi(rv2) + bfhi(xv3) + bfhi(rv3);
    }
    for (; e + 2 <= e1; e += 2) {
        int p0 = packed[e], p1 = packed[e + 1];
        uint xv0 = *(const uint*)(A + (p0 & 0xFFFF) * 256 + FEAT + lane * 2);
        uint rv0 = *(const uint*)(relb + (p0 >> 16) * FEAT + lane * 2);
        uint xv1 = *(const uint*)(A + (p1 & 0xFFFF) * 256 + FEAT + lane * 2);
        uint rv1 = *(const uint*)(relb + (p1 >> 16) * FEAT + lane * 2);
        ax += bflo(xv0) + bflo(rv0) + bflo(xv1) + bflo(rv1);
        ay += bfhi(xv0) + bfhi(rv0) + bfhi(xv1) + bfhi(rv1);
    }
    if (e < e1) {
        int p = packed[e];
        uint xv = *(const uint*)(A + (p & 0xFFFF) * 256 + FEAT + lane * 2);
        uint rv = *(const uint*)(relb + (p >> 16) * FEAT + lane * 2);
        ax += bflo(xv) + bflo(rv);
        ay += bfhi(xv) + bfhi(rv);
    }
    float invd = 1.0f / fmaxf((float)(e1 - e0), 1.0f);
    uint o = (uint)f2bf(ax * invd) | ((uint)f2bf(ay * invd) << 16);
    *(uint*)(A + node * 256 + lane * 2) = o;
}

// ---- hy: TM=32 (1564 blocks -> ~6 blocks/CU), fragment-major B, 16KB LDS.
__global__ __launch_bounds__(256) void k_hy(
    const ushort* __restrict__ A, const ushort* __restrict__ Wt1,
    const ushort* __restrict__ W1t,
    const float* __restrict__ bm, const float* __restrict__ b1,
    ushort* __restrict__ y, float* __restrict__ pb)
{
    __shared__ ushort a_s[32 * 256];      // 16 KB; swizzled 16B granules
    int tid = threadIdx.x;
    int w = tid >> 6, l = tid & 63;
    int lr = l & 15, lk = l >> 4;
    int m0 = blockIdx.x * 32;

    // stage A-tile (16KB): LDS linear, global source swizzled
    {
        const ushort* srcb = A + (size_t)m0 * 256;
        #pragma unroll
        for (int j = 0; j < 4; ++j) {
            int slot = (w * 4 + j) * 64 + l;
            int lrow = slot >> 5, lgr = slot & 31;
            GLL(srcb + lrow * 256 + ((lgr ^ (lrow & 7)) << 3), &a_s[(w * 4 + j) * 512]);
        }
    }
    __syncthreads();

    // ---- phase 1: h = [agg|x] @ [Wm;Wsf] (+bm)
    f32x4 acc[2][4] = {};
    const ushort* Bp = Wt1 + w * 16384 + l * 8;
    #pragma unroll
    for (int kk = 0; kk < 8; ++kk) {
        bf16x8 a[2], b[4];
        #pragma unroll
        for (int mb = 0; mb < 2; ++mb) {
            int row = mb * 16 + lr;
            a[mb] = *(const bf16x8*)&a_s[row * 256 + (((kk * 4 + lk) ^ (lr & 7)) << 3)];
        }
        #pragma unroll
        for (int nb = 0; nb < 4; ++nb) b[nb] = *(const bf16x8*)(Bp + kk * 2048 + nb * 512);
        #pragma unroll
        for (int mb = 0; mb < 2; ++mb)
            #pragma unroll
            for (int nb = 0; nb < 4; ++nb)
                acc[mb][nb] = MFMA(a[mb], b[nb], acc[mb][nb]);
    }
    __syncthreads();   // a_s reads done; reuse for h

    #pragma unroll
    for (int nb = 0; nb < 4; ++nb) {
        int col = w * 64 + nb * 16 + lr;
        float bias = bm[col];
        #pragma unroll
        for (int mb = 0; mb < 2; ++mb)
            #pragma unroll
            for (int r = 0; r < 4; ++r) {
                int row = mb * 16 + lk * 4 + r;
                a_s[row * 256 + (col ^ ((row & 7) << 3))] = f2bf(acc[mb][nb][r] + bias);
            }
    }
    __syncthreads();

    // ---- phase 2: y = h @ W1 (+b1)
    f32x4 acc2[2][4] = {};
    const ushort* B2p = W1t + w * 16384 + l * 8;
    #pragma unroll
    for (int kk = 0; kk < 8; ++kk) {
        bf16x8 a[2], b[4];
        #pragma unroll
        for (int mb = 0; mb < 2; ++mb) {
            int row = mb * 16 + lr;
            a[mb] = *(const bf16x8*)&a_s[row * 256 + ((kk * 32 + lk * 8) ^ ((row & 7) << 3))];
        }
        #pragma unroll
        for (int nb = 0; nb < 4; ++nb) b[nb] = *(const bf16x8*)(B2p + kk * 2048 + nb * 512);
        #pragma unroll
        for (int mb = 0; mb < 2; ++mb)
            #pragma unroll
            for (int nb = 0; nb < 4; ++nb)
                acc2[mb][nb] = MFMA(a[mb], b[nb], acc2[mb][nb]);
    }
    __syncthreads();   // h reads done; reuse a_s for y staging

    #pragma unroll
    for (int nb = 0; nb < 4; ++nb) {
        int col = w * 64 + nb * 16 + lr;
        float b1v = b1[col];
        float cs = 0.f, cq = 0.f;
        #pragma unroll
        for (int mb = 0; mb < 2; ++mb)
            #pragma unroll
            for (int r = 0; r < 4; ++r) {
                int row = mb * 16 + lk * 4 + r;
                float v = acc2[mb][nb][r] + b1v;
                if (m0 + row < N_ENT) { cs += v; cq += v * v; }
                a_s[row * 256 + (col ^ ((row & 7) << 3))] = f2bf(v);
            }
        cs += __shfl_xor(cs, 16); cs += __shfl_xor(cs, 32);
        cq += __shfl_xor(cq, 16); cq += __shfl_xor(cq, 32);
        if (lk == 0) {
            *(float2*)(pb + (size_t)blockIdx.x * 512 + col * 2) = make_float2(cs, cq);
        }
    }
    __syncthreads();
    ushort* yp = y + (size_t)m0 * 256;
    #pragma unroll
    for (int i = 0; i < 4; ++i) {
        int off = i * 2048 + tid * 8;
        *(uint4*)(yp + off) = *(const uint4*)&a_s[off];
    }
}

// ---- red1: parallel stage-1 reduce: 196 blocks x 8 tiles -> pb2[196][512]
__global__ __launch_bounds__(256) void k_red1(
    const float* __restrict__ pb, float* __restrict__ pb2)
{
    int b = blockIdx.x, tid = threadIdx.x;
    int t0 = b * 8;
    float sx = 0.f, sy = 0.f;
    #pragma unroll
    for (int i = 0; i < 8; ++i) {
        int t = t0 + i;
        if (t < NT32) {
            float2 v = *(const float2*)(pb + (size_t)t * 512 + tid * 2);
            sx += v.x; sy += v.y;
        }
    }
    *(float2*)(pb2 + (size_t)b * 512 + tid * 2) = make_float2(sx, sy);
}

// ---- red2: stage-2 reduce + BN finalize
__global__ __launch_bounds__(256) void k_red2(
    const float* __restrict__ pb2,
    const float* __restrict__ gamma, const float* __restrict__ beta,
    float* __restrict__ scale, float* __restrict__ shift)
{
    int c = threadIdx.x;
    float s = 0.f, q = 0.f;
    int b = 0;
    #pragma unroll
    for (; b + 8 <= RED_BLKS; b += 8) {
        float2 v0 = *(const float2*)(pb2 + (size_t)(b + 0) * 512 + c * 2);
        float2 v1 = *(const float2*)(pb2 + (size_t)(b + 1) * 512 + c * 2);
        float2 v2 = *(const float2*)(pb2 + (size_t)(b + 2) * 512 + c * 2);
        float2 v3 = *(const float2*)(pb2 + (size_t)(b + 3) * 512 + c * 2);
        float2 v4 = *(const float2*)(pb2 + (size_t)(b + 4) * 512 + c * 2);
        float2 v5 = *(const float2*)(pb2 + (size_t)(b + 5) * 512 + c * 2);
        float2 v6 = *(const float2*)(pb2 + (size_t)(b + 6) * 512 + c * 2);
        float2 v7 = *(const float2*)(pb2 + (size_t)(b + 7) * 512 + c * 2);
        s += v0.x + v1.x + v2.x + v3.x + v4.x + v5.x + v6.x + v7.x;
        q += v0.y + v1.y + v2.y + v3.y + v4.y + v5.y + v6.y + v7.y;
    }
    for (; b < RED_BLKS; ++b) {
        float2 v = *(const float2*)(pb2 + (size_t)b * 512 + c * 2);
        s += v.x; q += v.y;
    }
    const float invn = 1.0f / (float)N_ENT;
    float mean = s * invn;
    float var  = q * invn - mean * mean;
    float rstd = rsqrtf(var + BN_EPS);
    float sc   = gamma[c] * rstd;
    scale[c] = sc;
    shift[c] = beta[c] - mean * sc;
}

// ---- zout: TM=64, fragment-major B (r17 version).
__global__ __launch_bounds__(256) void k_zout(
    const ushort* __restrict__ y, const float* __restrict__ scale,
    const float* __restrict__ shift, const ushort* __restrict__ W2t,
    const float* __restrict__ b2, float* __restrict__ out)
{
    __shared__ ushort z_s[64 * 256];
    int tid = threadIdx.x;
    int w = tid >> 6, l = tid & 63;
    int lr = l & 15, lk = l >> 4;
    int m0 = blockIdx.x * 64;

    {
        const ushort* srcb = y + (size_t)m0 * 256;
        #pragma unroll
        for (int j = 0; j < 8; ++j)
            GLL(srcb + ((w * 8 + j) * 64 + l) * 8, &z_s[(w * 8 + j) * 512]);
    }
    __syncthreads();

    f32x4 acc[4][2] = {};
    const ushort* Bp = W2t + w * 8192 + l * 8;
    #pragma unroll
    for (int kk = 0; kk < 8; ++kk) {
        int kb = kk * 32 + lk * 8;
        float scv[8], shv[8];
        *(float4*)&scv[0] = *(const float4*)(scale + kb);
        *(float4*)&scv[4] = *(const float4*)(scale + kb + 4);
        *(float4*)&shv[0] = *(const float4*)(shift + kb);
        *(float4*)&shv[4] = *(const float4*)(shift + kb + 4);
        bf16x8 b[2];
        #pragma unroll
        for (int nb = 0; nb < 2; ++nb) b[nb] = *(const bf16x8*)(Bp + kk * 1024 + nb * 512);
        bf16x8 a[4];
        #pragma unroll
        for (int mb = 0; mb < 4; ++mb) {
            int row = mb * 16 + lr;
            uint4 uv = *(const uint4*)&z_s[row * 256 + (kb ^ ((row & 7) << 3))];
            uint wd[4] = {uv.x, uv.y, uv.z, uv.w};
            #pragma unroll
            for (int j = 0; j < 8; ++j) {
                uint bits = (j & 1) ? (wd[j >> 1] & 0xFFFF0000u) : (wd[j >> 1] << 16);
                float f = __uint_as_float(bits);
                float z = fmaxf(f * scv[j] + shv[j], 0.f);
                a[mb][j] = (short)f2bf(z);
            }
        }
        #pragma unroll
        for (int mb = 0; mb < 4; ++mb)
            #pragma unroll
            for (int nb = 0; nb < 2; ++nb)
                acc[mb][nb] = MFMA(a[mb], b[nb], acc[mb][nb]);
    }
    #pragma unroll
    for (int nb = 0; nb < 2; ++nb) {
        int col = w * 32 + nb * 16 + lr;
        float b2v = b2[col];
        #pragma unroll
        for (int mb = 0; mb < 4; ++mb)
            #pragma unroll
            for (int r = 0; r < 4; ++r) {
                int row = m0 + mb * 16 + lk * 4 + r;
                if (row < N_ENT) out[row * OUT_D + col] = acc[mb][nb][r] + b2v;
            }
    }
}

extern "C" void kernel_launch(void* const* d_in, const int* in_sizes, int n_in,
                              void* d_out, int out_size, void* d_ws, size_t ws_size,
                              hipStream_t stream)
{
    const int*   ei    = (const int*)d_in[0];
    const int*   et    = (const int*)d_in[1];
    const float* x     = (const float*)d_in[2];
    const float* rel   = (const float*)d_in[3];
    const float* Wm    = (const float*)d_in[4];
    const float* bm    = (const float*)d_in[5];
    const float* Wsf   = (const float*)d_in[6];
    const float* W1    = (const float*)d_in[7];
    const float* b1    = (const float*)d_in[8];
    const float* gamma = (const float*)d_in[9];
    const float* beta  = (const float*)d_in[10];
    const float* W2    = (const float*)d_in[11];
    const float* b2    = (const float*)d_in[12];
    float* out = (float*)d_out;

    char* ws = (char*)d_ws;
    int*    degi   = (int*)(ws + OFF_DEGI);
    float*  scale  = (float*)(ws + OFF_SCALE);
    float*  shift  = (float*)(ws + OFF_SHIFT);
    ushort* relb   = (ushort*)(ws + OFF_RELB);
    ushort* Wt1    = (ushort*)(ws + OFF_WT1);
    ushort* W1t    = (ushort*)(ws + OFF_W1T);
    ushort* W2t    = (ushort*)(ws + OFF_W2T);
    ushort* A      = (ushort*)(ws + OFF_A);
    ushort* y      = (ushort*)(ws + OFF_Y);
    int*    rowptr = (int*)(ws + OFF_ROWPTR);
    int*    fillc  = (int*)(ws + OFF_FILLC);
    int*    packed = (int*)(ws + OFF_PACKED);
    int*    bsum   = (int*)(ws + OFF_BSUM);
    int*    boff   = (int*)(ws + OFF_BOFF);
    float*  pb     = (float*)(ws + OFF_PB);
    float*  pb2    = (float*)(ws + OFF_PB2);

    hipMemsetAsync(ws + OFF_DEGI, 0, 200000, stream);

    k_prep <<<6160, 256, 0, stream>>>(x, ei, Wm, Wsf, W1, W2, rel, A, degi, Wt1, W1t, W2t, relb);
    k_bsum <<<SCAN_BLKS, 256, 0, stream>>>(degi, bsum);
    k_boff <<<1, 256, 0, stream>>>(bsum, boff, rowptr);
    k_scan2<<<SCAN_BLKS, 256, 0, stream>>>(degi, boff, rowptr, fillc);
    k_fill <<<(N_EDGE + 255) / 256, 256, 0, stream>>>(ei, et, fillc, packed);
    k_agg  <<<N_ENT / 4, 256, 0, stream>>>(rowptr, packed, A, relb);
    k_hy   <<<NT32, 256, 0, stream>>>(A, Wt1, W1t, bm, b1, y, pb);
    k_red1 <<<RED_BLKS, 256, 0, stream>>>(pb, pb2);
    k_red2 <<<1, 256, 0, stream>>>(pb2, gamma, beta, scale, shift);
    k_zout <<<NT64, 256, 0, stream>>>(y, scale, shift, W2t, b2, out);
}

// Round 20
// 168.964 us; speedup vs baseline: 1.1226x; 1.0467x over previous
//
#include <hip/hip_runtime.h>
#include <hip/hip_bf16.h>

#define N_ENT   50000
#define N_EDGE  600000
#define FEAT    128
#define HID     256
#define OUT_D   128
#define MROWS   50048        // N_ENT padded to 64
#define BN_EPS  1e-5f
#define SCAN_BLKS 196        // ceil(N_ENT/256)
#define NT32    (MROWS / 32) // 1564 row-tiles of 32
#define RED_BLKS 196         // ceil(NT32/8)

// ---------------- ws layout (bytes) ----------------
#define OFF_DEGI    0               // [N_ENT] i32          200,000
#define OFF_SCALE   202048          // [HID] f32            1,024
#define OFF_SHIFT   203072          // [HID] f32            1,024
#define OFF_RELB    204096          // [101][128] bf16      25,856
#define OFF_WT1     229952          // fragment-major packed WmWsf^T  131,072
#define OFF_W1T     361024          // fragment-major packed W1^T     131,072
#define OFF_W2T     492096          // fragment-major packed W2^T     65,536
#define OFF_A       557632          // [MROWS][256] bf16 ([agg|x], linear)  25,624,576
#define OFF_Y       26182208        // [MROWS][256] bf16 (swizzled granules) 25,624,576
#define OFF_PB      52000000        // [NT32][512] f32 partials 3,203,072
#define OFF_PB2     55210000        // [196][512] f32 stage-2 partials 401,408
// CSR in its own region (r12 lesson)
#define OFF_ROWPTR  56000000        // [N_ENT+1] i32 200,064
#define OFF_FILLC   56200064        // [N_ENT] i32   200,000
#define OFF_PACKED  56400064        // [N_EDGE] i32  2,400,000
#define OFF_BSUM    58800064        // [196] i32

typedef __attribute__((ext_vector_type(8))) short bf16x8;
typedef __attribute__((ext_vector_type(4))) float f32x4;

#define GLL(gp, lp) __builtin_amdgcn_global_load_lds( \
    (const __attribute__((address_space(1))) void*)(gp), \
    (__attribute__((address_space(3))) void*)(lp), 16, 0, 0)

#define MFMA(a, b, c) __builtin_amdgcn_mfma_f32_16x16x32_bf16((a), (b), (c), 0, 0, 0)

__device__ __forceinline__ ushort f2bf(float f) {
    uint u = __float_as_uint(f);
    return (ushort)((u + 0x7FFFu + ((u >> 16) & 1u)) >> 16);
}
__device__ __forceinline__ float bflo(uint u) { return __uint_as_float(u << 16); }
__device__ __forceinline__ float bfhi(uint u) { return __uint_as_float(u & 0xFFFF0000u); }

// ---- prep (fused): cvt x->A right half | deg histogram | weight pack (fragment-major)
__global__ __launch_bounds__(256) void k_prep(
    const float* __restrict__ x, const int* __restrict__ ei,
    const float* __restrict__ Wm, const float* __restrict__ Wsf,
    const float* __restrict__ W1, const float* __restrict__ W2,
    const float* __restrict__ rel,
    ushort* __restrict__ A, int* __restrict__ degi,
    ushort* __restrict__ Wt1, ushort* __restrict__ W1t,
    ushort* __restrict__ W2t, ushort* __restrict__ relb)
{
    int b = blockIdx.x;
    if (b < 3125) {
        int idx = b * 256 + threadIdx.x;          // 800,000 exactly
        int m = idx >> 4;
        int c = (idx & 15) * 8;
        float4 f0 = *(const float4*)(x + m * FEAT + c);
        float4 f1 = *(const float4*)(x + m * FEAT + c + 4);
        uint4 o;
        o.x = (uint)f2bf(f0.x) | ((uint)f2bf(f0.y) << 16);
        o.y = (uint)f2bf(f0.z) | ((uint)f2bf(f0.w) << 16);
        o.z = (uint)f2bf(f1.x) | ((uint)f2bf(f1.y) << 16);
        o.w = (uint)f2bf(f1.z) | ((uint)f2bf(f1.w) << 16);
        *(uint4*)(A + m * 256 + FEAT + c) = o;
    } else if (b < 3125 + 2344) {
        int e = (b - 3125) * 256 + threadIdx.x;
        if (e < N_EDGE) atomicAdd(&degi[ei[N_EDGE + e]], 1);
    } else {
        int idx = (b - 5469) * 256 + threadIdx.x;
        if (idx < 65536) {                 // Wt1 pack
            int n = idx >> 8, k = idx & 255;
            float v = (k < FEAT) ? Wm[k * HID + n] : Wsf[(k - FEAT) * HID + n];
            int w = n >> 6, nb = (n >> 4) & 3, lr = n & 15;
            int kk = k >> 5, lk = (k >> 3) & 3, j = k & 7;
            int l = lk * 16 + lr;
            Wt1[(((w * 8 + kk) * 4 + nb) * 64 + l) * 8 + j] = f2bf(v);
        } else if (idx < 131072) {         // W1t pack
            int o = idx - 65536;
            int n = o >> 8, k = o & 255;
            float v = W1[k * HID + n];
            int w = n >> 6, nb = (n >> 4) & 3, lr = n & 15;
            int kk = k >> 5, lk = (k >> 3) & 3, j = k & 7;
            int l = lk * 16 + lr;
            W1t[(((w * 8 + kk) * 4 + nb) * 64 + l) * 8 + j] = f2bf(v);
        } else if (idx < 163840) {         // W2t pack
            int o = idx - 131072;
            int n = o >> 8, k = o & 255;
            float v = W2[k * OUT_D + n];
            int w = n >> 5, nb = (n >> 4) & 1, lr = n & 15;
            int kk = k >> 5, lk = (k >> 3) & 3, j = k & 7;
            int l = lk * 16 + lr;
            W2t[(((w * 8 + kk) * 2 + nb) * 64 + l) * 8 + j] = f2bf(v);
        } else if (idx < 163840 + 101 * 128) {
            int o = idx - 163840;
            relb[o] = f2bf(rel[o]);
        }
    }
}

// ---- bsum: per-block degree sums
__global__ __launch_bounds__(256) void k_bsum(
    const int* __restrict__ degi, int* __restrict__ bsum)
{
    __shared__ int red[4];
    int idx = blockIdx.x * 256 + threadIdx.x;
    int v = (idx < N_ENT) ? degi[idx] : 0;
    #pragma unroll
    for (int off = 1; off < 64; off <<= 1) v += __shfl_xor(v, off);
    if ((threadIdx.x & 63) == 0) red[threadIdx.x >> 6] = v;
    __syncthreads();
    if (threadIdx.x == 0) bsum[blockIdx.x] = red[0] + red[1] + red[2] + red[3];
}

// ---- scan2 (boff folded in): each block derives its offset from bsum directly
__global__ __launch_bounds__(256) void k_scan2(
    const int* __restrict__ degi, const int* __restrict__ bsum,
    int* __restrict__ rowptr, int* __restrict__ fillc)
{
    __shared__ int s[256];
    __shared__ int pre[256];
    int t = threadIdx.x;
    // block offset = sum of bsum[0..blockIdx.x)
    pre[t] = (t < blockIdx.x) ? bsum[t] : 0;     // blockIdx.x <= 195 < 256
    __syncthreads();
    #pragma unroll
    for (int off = 128; off >= 1; off >>= 1) {
        if (t < off) pre[t] += pre[t + off];
        __syncthreads();
    }
    int boff = pre[0];

    int idx = blockIdx.x * 256 + t;
    int v = (idx < N_ENT) ? degi[idx] : 0;
    s[t] = v;
    __syncthreads();
    for (int off = 1; off < 256; off <<= 1) {
        int u = (t >= off) ? s[t - off] : 0;
        __syncthreads();
        s[t] += u;
        __syncthreads();
    }
    if (idx < N_ENT) {
        int ex = s[t] - v + boff;
        rowptr[idx] = ex;
        fillc[idx]  = ex;
    }
    if (blockIdx.x == SCAN_BLKS - 1 && t == 255) rowptr[N_ENT] = boff + s[255];
}

__global__ __launch_bounds__(256) void k_fill(
    const int* __restrict__ ei, const int* __restrict__ et,
    int* __restrict__ fillc, int* __restrict__ packed)
{
    int e = blockIdx.x * 256 + threadIdx.x;
    if (e >= N_EDGE) return;
    int dst = ei[N_EDGE + e];
    int pos = atomicAdd(&fillc[dst], 1);
    packed[pos] = ei[e] | (et[e] << 16);
}

// ---- agg: segment mean, one node/wave; 8/4/2/1 MLP ladder
__global__ __launch_bounds__(256) void k_agg(
    const int* __restrict__ rowptr, const int* __restrict__ packed,
    ushort* __restrict__ A, const ushort* __restrict__ relb)
{
    int node = blockIdx.x * 4 + (threadIdx.x >> 6);
    int lane = threadIdx.x & 63;
    int e0 = rowptr[node], e1 = rowptr[node + 1];
    float ax = 0.f, ay = 0.f;
    int e = e0;
    for (; e + 8 <= e1; e += 8) {
        int p0 = packed[e],     p1 = packed[e + 1], p2 = packed[e + 2], p3 = packed[e + 3];
        int p4 = packed[e + 4], p5 = packed[e + 5], p6 = packed[e + 6], p7 = packed[e + 7];
        uint xv0 = *(const uint*)(A + (p0 & 0xFFFF) * 256 + FEAT + lane * 2);
        uint rv0 = *(const uint*)(relb + (p0 >> 16) * FEAT + lane * 2);
        uint xv1 = *(const uint*)(A + (p1 & 0xFFFF) * 256 + FEAT + lane * 2);
        uint rv1 = *(const uint*)(relb + (p1 >> 16) * FEAT + lane * 2);
        uint xv2 = *(const uint*)(A + (p2 & 0xFFFF) * 256 + FEAT + lane * 2);
        uint rv2 = *(const uint*)(relb + (p2 >> 16) * FEAT + lane * 2);
        uint xv3 = *(const uint*)(A + (p3 & 0xFFFF) * 256 + FEAT + lane * 2);
        uint rv3 = *(const uint*)(relb + (p3 >> 16) * FEAT + lane * 2);
        uint xv4 = *(const uint*)(A + (p4 & 0xFFFF) * 256 + FEAT + lane * 2);
        uint rv4 = *(const uint*)(relb + (p4 >> 16) * FEAT + lane * 2);
        uint xv5 = *(const uint*)(A + (p5 & 0xFFFF) * 256 + FEAT + lane * 2);
        uint rv5 = *(const uint*)(relb + (p5 >> 16) * FEAT + lane * 2);
        uint xv6 = *(const uint*)(A + (p6 & 0xFFFF) * 256 + FEAT + lane * 2);
        uint rv6 = *(const uint*)(relb + (p6 >> 16) * FEAT + lane * 2);
        uint xv7 = *(const uint*)(A + (p7 & 0xFFFF) * 256 + FEAT + lane * 2);
        uint rv7 = *(const uint*)(relb + (p7 >> 16) * FEAT + lane * 2);
        ax += bflo(xv0) + bflo(rv0) + bflo(xv1) + bflo(rv1)
            + bflo(xv2) + bflo(rv2) + bflo(xv3) + bflo(rv3)
            + bflo(xv4) + bflo(rv4) + bflo(xv5) + bflo(rv5)
            + bflo(xv6) + bflo(rv6) + bflo(xv7) + bflo(rv7);
        ay += bfhi(xv0) + bfhi(rv0) + bfhi(xv1) + bfhi(rv1)
            + bfhi(xv2) + bfhi(rv2) + bfhi(xv3) + bfhi(rv3)
            + bfhi(xv4) + bfhi(rv4) + bfhi(xv5) + bfhi(rv5)
            + bfhi(xv6) + bfhi(rv6) + bfhi(xv7) + bfhi(rv7);
    }
    for (; e + 4 <= e1; e += 4) {
        int p0 = packed[e], p1 = packed[e + 1], p2 = packed[e + 2], p3 = packed[e + 3];
        uint xv0 = *(const uint*)(A + (p0 & 0xFFFF) * 256 + FEAT + lane * 2);
        uint rv0 = *(const uint*)(relb + (p0 >> 16) * FEAT + lane * 2);
        uint xv1 = *(const uint*)(A + (p1 & 0xFFFF) * 256 + FEAT + lane * 2);
        uint rv1 = *(const uint*)(relb + (p1 >> 16) * FEAT + lane * 2);
        uint xv2 = *(const uint*)(A + (p2 & 0xFFFF) * 256 + FEAT + lane * 2);
        uint rv2 = *(const uint*)(relb + (p2 >> 16) * FEAT + lane * 2);
        uint xv3 = *(const uint*)(A + (p3 & 0xFFFF) * 256 + FEAT + lane * 2);
        uint rv3 = *(const uint*)(relb + (p3 >> 16) * FEAT + lane * 2);
        ax += bflo(xv0) + bflo(rv0) + bflo(xv1) + bflo(rv1)
            + bflo(xv2) + bflo(rv2) + bflo(xv3) + bflo(rv3);
        ay += bfhi(xv0) + bfhi(rv0) + bfhi(xv1) + bfhi(rv1)
            + bfhi(xv2) + bfhi(rv2) + bfhi(xv3) + bfhi(rv3);
    }
    for (; e + 2 <= e1; e += 2) {
        int p0 = packed[e], p1 = packed[e + 1];
        uint xv0 = *(const uint*)(A + (p0 & 0xFFFF) * 256 + FEAT + lane * 2);
        uint rv0 = *(const uint*)(relb + (p0 >> 16) * FEAT + lane * 2);
        uint xv1 = *(const uint*)(A + (p1 & 0xFFFF) * 256 + FEAT + lane * 2);
        uint rv1 = *(const uint*)(relb + (p1 >> 16) * FEAT + lane * 2);
        ax += bflo(xv0) + bflo(rv0) + bflo(xv1) + bflo(rv1);
        ay += bfhi(xv0) + bfhi(rv0) + bfhi(xv1) + bfhi(rv1);
    }
    if (e < e1) {
        int p = packed[e];
        uint xv = *(const uint*)(A + (p & 0xFFFF) * 256 + FEAT + lane * 2);
        uint rv = *(const uint*)(relb + (p >> 16) * FEAT + lane * 2);
        ax += bflo(xv) + bflo(rv);
        ay += bfhi(xv) + bfhi(rv);
    }
    float invd = 1.0f / fmaxf((float)(e1 - e0), 1.0f);
    uint o = (uint)f2bf(ax * invd) | ((uint)f2bf(ay * invd) << 16);
    *(uint*)(A + node * 256 + lane * 2) = o;
}

// ---- hy: TM=32, fragment-major B, 16KB LDS (r19 version).
__global__ __launch_bounds__(256) void k_hy(
    const ushort* __restrict__ A, const ushort* __restrict__ Wt1,
    const ushort* __restrict__ W1t,
    const float* __restrict__ bm, const float* __restrict__ b1,
    ushort* __restrict__ y, float* __restrict__ pb)
{
    __shared__ ushort a_s[32 * 256];      // 16 KB
    int tid = threadIdx.x;
    int w = tid >> 6, l = tid & 63;
    int lr = l & 15, lk = l >> 4;
    int m0 = blockIdx.x * 32;

    {
        const ushort* srcb = A + (size_t)m0 * 256;
        #pragma unroll
        for (int j = 0; j < 4; ++j) {
            int slot = (w * 4 + j) * 64 + l;
            int lrow = slot >> 5, lgr = slot & 31;
            GLL(srcb + lrow * 256 + ((lgr ^ (lrow & 7)) << 3), &a_s[(w * 4 + j) * 512]);
        }
    }
    __syncthreads();

    f32x4 acc[2][4] = {};
    const ushort* Bp = Wt1 + w * 16384 + l * 8;
    #pragma unroll
    for (int kk = 0; kk < 8; ++kk) {
        bf16x8 a[2], b[4];
        #pragma unroll
        for (int mb = 0; mb < 2; ++mb) {
            int row = mb * 16 + lr;
            a[mb] = *(const bf16x8*)&a_s[row * 256 + (((kk * 4 + lk) ^ (lr & 7)) << 3)];
        }
        #pragma unroll
        for (int nb = 0; nb < 4; ++nb) b[nb] = *(const bf16x8*)(Bp + kk * 2048 + nb * 512);
        #pragma unroll
        for (int mb = 0; mb < 2; ++mb)
            #pragma unroll
            for (int nb = 0; nb < 4; ++nb)
                acc[mb][nb] = MFMA(a[mb], b[nb], acc[mb][nb]);
    }
    __syncthreads();

    #pragma unroll
    for (int nb = 0; nb < 4; ++nb) {
        int col = w * 64 + nb * 16 + lr;
        float bias = bm[col];
        #pragma unroll
        for (int mb = 0; mb < 2; ++mb)
            #pragma unroll
            for (int r = 0; r < 4; ++r) {
                int row = mb * 16 + lk * 4 + r;
                a_s[row * 256 + (col ^ ((row & 7) << 3))] = f2bf(acc[mb][nb][r] + bias);
            }
    }
    __syncthreads();

    f32x4 acc2[2][4] = {};
    const ushort* B2p = W1t + w * 16384 + l * 8;
    #pragma unroll
    for (int kk = 0; kk < 8; ++kk) {
        bf16x8 a[2], b[4];
        #pragma unroll
        for (int mb = 0; mb < 2; ++mb) {
            int row = mb * 16 + lr;
            a[mb] = *(const bf16x8*)&a_s[row * 256 + ((kk * 32 + lk * 8) ^ ((row & 7) << 3))];
        }
        #pragma unroll
        for (int nb = 0; nb < 4; ++nb) b[nb] = *(const bf16x8*)(B2p + kk * 2048 + nb * 512);
        #pragma unroll
        for (int mb = 0; mb < 2; ++mb)
            #pragma unroll
            for (int nb = 0; nb < 4; ++nb)
                acc2[mb][nb] = MFMA(a[mb], b[nb], acc2[mb][nb]);
    }
    __syncthreads();

    #pragma unroll
    for (int nb = 0; nb < 4; ++nb) {
        int col = w * 64 + nb * 16 + lr;
        float b1v = b1[col];
        float cs = 0.f, cq = 0.f;
        #pragma unroll
        for (int mb = 0; mb < 2; ++mb)
            #pragma unroll
            for (int r = 0; r < 4; ++r) {
                int row = mb * 16 + lk * 4 + r;
                float v = acc2[mb][nb][r] + b1v;
                if (m0 + row < N_ENT) { cs += v; cq += v * v; }
                a_s[row * 256 + (col ^ ((row & 7) << 3))] = f2bf(v);
            }
        cs += __shfl_xor(cs, 16); cs += __shfl_xor(cs, 32);
        cq += __shfl_xor(cq, 16); cq += __shfl_xor(cq, 32);
        if (lk == 0) {
            *(float2*)(pb + (size_t)blockIdx.x * 512 + col * 2) = make_float2(cs, cq);
        }
    }
    __syncthreads();
    ushort* yp = y + (size_t)m0 * 256;
    #pragma unroll
    for (int i = 0; i < 4; ++i) {
        int off = i * 2048 + tid * 8;
        *(uint4*)(yp + off) = *(const uint4*)&a_s[off];
    }
}

// ---- red1: 196 blocks x 8 tiles -> pb2
__global__ __launch_bounds__(256) void k_red1(
    const float* __restrict__ pb, float* __restrict__ pb2)
{
    int b = blockIdx.x, tid = threadIdx.x;
    int t0 = b * 8;
    float sx = 0.f, sy = 0.f;
    #pragma unroll
    for (int i = 0; i < 8; ++i) {
        int t = t0 + i;
        if (t < NT32) {
            float2 v = *(const float2*)(pb + (size_t)t * 512 + tid * 2);
            sx += v.x; sy += v.y;
        }
    }
    *(float2*)(pb2 + (size_t)b * 512 + tid * 2) = make_float2(sx, sy);
}

// ---- red2: stage-2 reduce + BN finalize
__global__ __launch_bounds__(256) void k_red2(
    const float* __restrict__ pb2,
    const float* __restrict__ gamma, const float* __restrict__ beta,
    float* __restrict__ scale, float* __restrict__ shift)
{
    int c = threadIdx.x;
    float s = 0.f, q = 0.f;
    int b = 0;
    #pragma unroll
    for (; b + 8 <= RED_BLKS; b += 8) {
        float2 v0 = *(const float2*)(pb2 + (size_t)(b + 0) * 512 + c * 2);
        float2 v1 = *(const float2*)(pb2 + (size_t)(b + 1) * 512 + c * 2);
        float2 v2 = *(const float2*)(pb2 + (size_t)(b + 2) * 512 + c * 2);
        float2 v3 = *(const float2*)(pb2 + (size_t)(b + 3) * 512 + c * 2);
        float2 v4 = *(const float2*)(pb2 + (size_t)(b + 4) * 512 + c * 2);
        float2 v5 = *(const float2*)(pb2 + (size_t)(b + 5) * 512 + c * 2);
        float2 v6 = *(const float2*)(pb2 + (size_t)(b + 6) * 512 + c * 2);
        float2 v7 = *(const float2*)(pb2 + (size_t)(b + 7) * 512 + c * 2);
        s += v0.x + v1.x + v2.x + v3.x + v4.x + v5.x + v6.x + v7.x;
        q += v0.y + v1.y + v2.y + v3.y + v4.y + v5.y + v6.y + v7.y;
    }
    for (; b < RED_BLKS; ++b) {
        float2 v = *(const float2*)(pb2 + (size_t)b * 512 + c * 2);
        s += v.x; q += v.y;
    }
    const float invn = 1.0f / (float)N_ENT;
    float mean = s * invn;
    float var  = q * invn - mean * mean;
    float rstd = rsqrtf(var + BN_EPS);
    float sc   = gamma[c] * rstd;
    scale[c] = sc;
    shift[c] = beta[c] - mean * sc;
}

// ---- zout: TM=32 (mirrors k_hy's validated structure), fragment-major B.
__global__ __launch_bounds__(256) void k_zout(
    const ushort* __restrict__ y, const float* __restrict__ scale,
    const float* __restrict__ shift, const ushort* __restrict__ W2t,
    const float* __restrict__ b2, float* __restrict__ out)
{
    __shared__ ushort z_s[32 * 256];      // 16 KB
    int tid = threadIdx.x;
    int w = tid >> 6, l = tid & 63;
    int lr = l & 15, lk = l >> 4;
    int m0 = blockIdx.x * 32;

    {
        const ushort* srcb = y + (size_t)m0 * 256;
        #pragma unroll
        for (int j = 0; j < 4; ++j)
            GLL(srcb + ((w * 4 + j) * 64 + l) * 8, &z_s[(w * 4 + j) * 512]);
    }
    __syncthreads();

    f32x4 acc[2][2] = {};
    const ushort* Bp = W2t + w * 8192 + l * 8;
    #pragma unroll
    for (int kk = 0; kk < 8; ++kk) {
        int kb = kk * 32 + lk * 8;
        float scv[8], shv[8];
        *(float4*)&scv[0] = *(const float4*)(scale + kb);
        *(float4*)&scv[4] = *(const float4*)(scale + kb + 4);
        *(float4*)&shv[0] = *(const float4*)(shift + kb);
        *(float4*)&shv[4] = *(const float4*)(shift + kb + 4);
        bf16x8 b[2];
        #pragma unroll
        for (int nb = 0; nb < 2; ++nb) b[nb] = *(const bf16x8*)(Bp + kk * 1024 + nb * 512);
        bf16x8 a[2];
        #pragma unroll
        for (int mb = 0; mb < 2; ++mb) {
            int row = mb * 16 + lr;
            uint4 uv = *(const uint4*)&z_s[row * 256 + (kb ^ ((row & 7) << 3))];
            uint wd[4] = {uv.x, uv.y, uv.z, uv.w};
            #pragma unroll
            for (int j = 0; j < 8; ++j) {
                uint bits = (j & 1) ? (wd[j >> 1] & 0xFFFF0000u) : (wd[j >> 1] << 16);
                float f = __uint_as_float(bits);
                float z = fmaxf(f * scv[j] + shv[j], 0.f);
                a[mb][j] = (short)f2bf(z);
            }
        }
        #pragma unroll
        for (int mb = 0; mb < 2; ++mb)
            #pragma unroll
            for (int nb = 0; nb < 2; ++nb)
                acc[mb][nb] = MFMA(a[mb], b[nb], acc[mb][nb]);
    }
    #pragma unroll
    for (int nb = 0; nb < 2; ++nb) {
        int col = w * 32 + nb * 16 + lr;
        float b2v = b2[col];
        #pragma unroll
        for (int mb = 0; mb < 2; ++mb)
            #pragma unroll
            for (int r = 0; r < 4; ++r) {
                int row = m0 + mb * 16 + lk * 4 + r;
                if (row < N_ENT) out[row * OUT_D + col] = acc[mb][nb][r] + b2v;
            }
    }
}

extern "C" void kernel_launch(void* const* d_in, const int* in_sizes, int n_in,
                              void* d_out, int out_size, void* d_ws, size_t ws_size,
                              hipStream_t stream)
{
    const int*   ei    = (const int*)d_in[0];
    const int*   et    = (const int*)d_in[1];
    const float* x     = (const float*)d_in[2];
    const float* rel   = (const float*)d_in[3];
    const float* Wm    = (const float*)d_in[4];
    const float* bm    = (const float*)d_in[5];
    const float* Wsf   = (const float*)d_in[6];
    const float* W1    = (const float*)d_in[7];
    const float* b1    = (const float*)d_in[8];
    const float* gamma = (const float*)d_in[9];
    const float* beta  = (const float*)d_in[10];
    const float* W2    = (const float*)d_in[11];
    const float* b2    = (const float*)d_in[12];
    float* out = (float*)d_out;

    char* ws = (char*)d_ws;
    int*    degi   = (int*)(ws + OFF_DEGI);
    float*  scale  = (float*)(ws + OFF_SCALE);
    float*  shift  = (float*)(ws + OFF_SHIFT);
    ushort* relb   = (ushort*)(ws + OFF_RELB);
    ushort* Wt1    = (ushort*)(ws + OFF_WT1);
    ushort* W1t    = (ushort*)(ws + OFF_W1T);
    ushort* W2t    = (ushort*)(ws + OFF_W2T);
    ushort* A      = (ushort*)(ws + OFF_A);
    ushort* y      = (ushort*)(ws + OFF_Y);
    int*    rowptr = (int*)(ws + OFF_ROWPTR);
    int*    fillc  = (int*)(ws + OFF_FILLC);
    int*    packed = (int*)(ws + OFF_PACKED);
    int*    bsum   = (int*)(ws + OFF_BSUM);
    float*  pb     = (float*)(ws + OFF_PB);
    float*  pb2    = (float*)(ws + OFF_PB2);

    hipMemsetAsync(ws + OFF_DEGI, 0, 200000, stream);

    k_prep <<<6160, 256, 0, stream>>>(x, ei, Wm, Wsf, W1, W2, rel, A, degi, Wt1, W1t, W2t, relb);
    k_bsum <<<SCAN_BLKS, 256, 0, stream>>>(degi, bsum);
    k_scan2<<<SCAN_BLKS, 256, 0, stream>>>(degi, bsum, rowptr, fillc);
    k_fill <<<(N_EDGE + 255) / 256, 256, 0, stream>>>(ei, et, fillc, packed);
    k_agg  <<<N_ENT / 4, 256, 0, stream>>>(rowptr, packed, A, relb);
    k_hy   <<<NT32, 256, 0, stream>>>(A, Wt1, W1t, bm, b1, y, pb);
    k_red1 <<<RED_BLKS, 256, 0, stream>>>(pb, pb2);
    k_red2 <<<1, 256, 0, stream>>>(pb2, gamma, beta, scale, shift);
    k_zout <<<NT32, 256, 0, stream>>>(y, scale, shift, W2t, b2, out);
}

// Round 21
// 151.004 us; speedup vs baseline: 1.2561x; 1.1189x over previous
//
#include <hip/hip_runtime.h>
#include <hip/hip_bf16.h>

#define N_ENT   50000
#define N_EDGE  600000
#define FEAT    128
#define HID     256
#define OUT_D   128
#define MROWS   50048        // N_ENT padded to 64
#define BN_EPS  1e-5f
#define NT32    (MROWS / 32) // 1564 row-tiles of 32
#define RED_BLKS 196         // ceil(NT32/8)
#define NBUCK   196          // coarse buckets (dst >> 8)
#define EPB     4096         // edges per chist/cscat block
#define NBLK_E  147          // ceil(N_EDGE / EPB)

// ---------------- ws layout (bytes) ----------------
#define OFF_SCALE   202048          // [HID] f32
#define OFF_SHIFT   203072          // [HID] f32
#define OFF_RELB    204096          // [101][128] bf16
#define OFF_WT1     229952          // fragment-major packed WmWsf^T  131,072
#define OFF_W1T     361024          // fragment-major packed W1^T     131,072
#define OFF_W2T     492096          // fragment-major packed W2^T     65,536
#define OFF_A       557632          // [MROWS][256] bf16 ([agg|x], linear)
#define OFF_Y       26182208        // [MROWS][256] bf16 (swizzled granules)
#define OFF_PB      52000000        // [NT32][512] f32 partials
#define OFF_PB2     55210000        // [196][512] f32 stage-2 partials
#define OFF_ROWPTR  56000000        // [N_ENT+1] i32
#define OFF_PACKED  56400064        // [N_EDGE] i32 (src | type<<16), dst-sorted
#define OFF_EBUF    58900000        // [N_EDGE] i32 coarse-bucketed
#define OFF_CHIST   61300000        // [NBLK_E][NBUCK] i32
#define OFF_OFFA    61420000        // [NBLK_E][NBUCK] i32 (per-block in-bucket prefix)
#define OFF_CBASE   61540000        // [NBUCK+1] i32

typedef __attribute__((ext_vector_type(8))) short bf16x8;
typedef __attribute__((ext_vector_type(4))) float f32x4;

#define GLL(gp, lp) __builtin_amdgcn_global_load_lds( \
    (const __attribute__((address_space(1))) void*)(gp), \
    (__attribute__((address_space(3))) void*)(lp), 16, 0, 0)

#define MFMA(a, b, c) __builtin_amdgcn_mfma_f32_16x16x32_bf16((a), (b), (c), 0, 0, 0)

__device__ __forceinline__ ushort f2bf(float f) {
    uint u = __float_as_uint(f);
    return (ushort)((u + 0x7FFFu + ((u >> 16) & 1u)) >> 16);
}
__device__ __forceinline__ float bflo(uint u) { return __uint_as_float(u << 16); }
__device__ __forceinline__ float bfhi(uint u) { return __uint_as_float(u & 0xFFFF0000u); }

// ---- prep: cvt x->A right half | weight pack (fragment-major). NO histogram.
__global__ __launch_bounds__(256) void k_prep(
    const float* __restrict__ x,
    const float* __restrict__ Wm, const float* __restrict__ Wsf,
    const float* __restrict__ W1, const float* __restrict__ W2,
    const float* __restrict__ rel,
    ushort* __restrict__ A,
    ushort* __restrict__ Wt1, ushort* __restrict__ W1t,
    ushort* __restrict__ W2t, ushort* __restrict__ relb)
{
    int b = blockIdx.x;
    if (b < 3125) {
        int idx = b * 256 + threadIdx.x;          // 800,000 exactly
        int m = idx >> 4;
        int c = (idx & 15) * 8;
        float4 f0 = *(const float4*)(x + m * FEAT + c);
        float4 f1 = *(const float4*)(x + m * FEAT + c + 4);
        uint4 o;
        o.x = (uint)f2bf(f0.x) | ((uint)f2bf(f0.y) << 16);
        o.y = (uint)f2bf(f0.z) | ((uint)f2bf(f0.w) << 16);
        o.z = (uint)f2bf(f1.x) | ((uint)f2bf(f1.y) << 16);
        o.w = (uint)f2bf(f1.z) | ((uint)f2bf(f1.w) << 16);
        *(uint4*)(A + m * 256 + FEAT + c) = o;
    } else {
        int idx = (b - 3125) * 256 + threadIdx.x;
        if (idx < 65536) {                 // Wt1 pack
            int n = idx >> 8, k = idx & 255;
            float v = (k < FEAT) ? Wm[k * HID + n] : Wsf[(k - FEAT) * HID + n];
            int w = n >> 6, nb = (n >> 4) & 3, lr = n & 15;
            int kk = k >> 5, lk = (k >> 3) & 3, j = k & 7;
            int l = lk * 16 + lr;
            Wt1[(((w * 8 + kk) * 4 + nb) * 64 + l) * 8 + j] = f2bf(v);
        } else if (idx < 131072) {         // W1t pack
            int o = idx - 65536;
            int n = o >> 8, k = o & 255;
            float v = W1[k * HID + n];
            int w = n >> 6, nb = (n >> 4) & 3, lr = n & 15;
            int kk = k >> 5, lk = (k >> 3) & 3, j = k & 7;
            int l = lk * 16 + lr;
            W1t[(((w * 8 + kk) * 4 + nb) * 64 + l) * 8 + j] = f2bf(v);
        } else if (idx < 163840) {         // W2t pack
            int o = idx - 131072;
            int n = o >> 8, k = o & 255;
            float v = W2[k * OUT_D + n];
            int w = n >> 5, nb = (n >> 4) & 1, lr = n & 15;
            int kk = k >> 5, lk = (k >> 3) & 3, j = k & 7;
            int l = lk * 16 + lr;
            W2t[(((w * 8 + kk) * 2 + nb) * 64 + l) * 8 + j] = f2bf(v);
        } else if (idx < 163840 + 101 * 128) {
            int o = idx - 163840;
            relb[o] = f2bf(rel[o]);
        }
    }
}

// ---- chist: per-block coarse histogram (LDS atomics only)
__global__ __launch_bounds__(256) void k_chist(
    const int* __restrict__ ei, int* __restrict__ chist)
{
    __shared__ int h[NBUCK];
    int t = threadIdx.x;
    if (t < NBUCK) h[t] = 0;
    __syncthreads();
    #pragma unroll
    for (int r = 0; r < 16; ++r) {
        int e = (blockIdx.x * 16 + r) * 256 + t;
        if (e < N_EDGE) atomicAdd(&h[ei[N_EDGE + e] >> 8], 1);
    }
    __syncthreads();
    if (t < NBUCK) chist[blockIdx.x * NBUCK + t] = h[t];
}

// ---- cscan: thread k: prefix over blocks for bucket k; then scan totals -> cbase
__global__ __launch_bounds__(256) void k_cscan(
    const int* __restrict__ chist, int* __restrict__ offa, int* __restrict__ cbase)
{
    __shared__ int s[256];
    int k = threadIdx.x;
    int acc = 0;
    if (k < NBUCK) {
        #pragma unroll 4
        for (int b = 0; b < NBLK_E; ++b) {
            offa[b * NBUCK + k] = acc;
            acc += chist[b * NBUCK + k];
        }
    }
    s[k] = (k < NBUCK) ? acc : 0;
    int v = s[k];
    __syncthreads();
    for (int off = 1; off < 256; off <<= 1) {
        int u = (k >= off) ? s[k - off] : 0;
        __syncthreads();
        s[k] += u;
        __syncthreads();
    }
    if (k < NBUCK) cbase[k] = s[k] - v;         // exclusive
    if (k == NBUCK - 1) cbase[NBUCK] = s[k];    // total = N_EDGE
}

// ---- cscat: scatter edges into coarse buckets (LDS running counters)
__global__ __launch_bounds__(256) void k_cscat(
    const int* __restrict__ ei, const int* __restrict__ et,
    const int* __restrict__ offa, const int* __restrict__ cbase,
    int* __restrict__ ebuf)
{
    __shared__ int base[NBUCK];
    int t = threadIdx.x;
    if (t < NBUCK) base[t] = offa[blockIdx.x * NBUCK + t] + cbase[t];
    __syncthreads();
    #pragma unroll
    for (int r = 0; r < 16; ++r) {
        int e = (blockIdx.x * 16 + r) * 256 + t;
        if (e < N_EDGE) {
            int dst = ei[N_EDGE + e];
            int k = dst >> 8;
            int pos = atomicAdd(&base[k], 1);
            ebuf[pos] = ei[e] | (et[e] << 16) | ((dst & 255) << 23);
        }
    }
}

// ---- fine: per-bucket count + scan -> rowptr; rank-scatter -> packed (sorted)
__global__ __launch_bounds__(256) void k_fine(
    const int* __restrict__ ebuf, const int* __restrict__ cbase,
    int* __restrict__ rowptr, int* __restrict__ packed)
{
    __shared__ int cnt[256], sc[256];
    int t = threadIdx.x, b = blockIdx.x;
    int s0 = cbase[b], s1 = cbase[b + 1];
    cnt[t] = 0;
    __syncthreads();
    for (int e = s0 + t; e < s1; e += 256)
        atomicAdd(&cnt[(ebuf[e] >> 23) & 255], 1);
    __syncthreads();
    int v = cnt[t];
    sc[t] = v;
    __syncthreads();
    for (int off = 1; off < 256; off <<= 1) {
        int u = (t >= off) ? sc[t - off] : 0;
        __syncthreads();
        sc[t] += u;
        __syncthreads();
    }
    int ex = sc[t] - v;
    int node = b * 256 + t;
    if (node < N_ENT) rowptr[node] = s0 + ex;
    if (b == NBUCK - 1 && t == 0) rowptr[N_ENT] = s1;
    __syncthreads();
    cnt[t] = s0 + ex;           // running counters
    __syncthreads();
    for (int e = s0 + t; e < s1; e += 256) {
        int v32 = ebuf[e];
        int pos = atomicAdd(&cnt[(v32 >> 23) & 255], 1);
        packed[pos] = v32 & 0x7FFFFF;       // src | type<<16
    }
}

// ---- agg: segment mean, one node/wave; 8/4/2/1 MLP ladder (unchanged)
__global__ __launch_bounds__(256) void k_agg(
    const int* __restrict__ rowptr, const int* __restrict__ packed,
    ushort* __restrict__ A, const ushort* __restrict__ relb)
{
    int node = blockIdx.x * 4 + (threadIdx.x >> 6);
    int lane = threadIdx.x & 63;
    int e0 = rowptr[node], e1 = rowptr[node + 1];
    float ax = 0.f, ay = 0.f;
    int e = e0;
    for (; e + 8 <= e1; e += 8) {
        int p0 = packed[e],     p1 = packed[e + 1], p2 = packed[e + 2], p3 = packed[e + 3];
        int p4 = packed[e + 4], p5 = packed[e + 5], p6 = packed[e + 6], p7 = packed[e + 7];
        uint xv0 = *(const uint*)(A + (p0 & 0xFFFF) * 256 + FEAT + lane * 2);
        uint rv0 = *(const uint*)(relb + (p0 >> 16) * FEAT + lane * 2);
        uint xv1 = *(const uint*)(A + (p1 & 0xFFFF) * 256 + FEAT + lane * 2);
        uint rv1 = *(const uint*)(relb + (p1 >> 16) * FEAT + lane * 2);
        uint xv2 = *(const uint*)(A + (p2 & 0xFFFF) * 256 + FEAT + lane * 2);
        uint rv2 = *(const uint*)(relb + (p2 >> 16) * FEAT + lane * 2);
        uint xv3 = *(const uint*)(A + (p3 & 0xFFFF) * 256 + FEAT + lane * 2);
        uint rv3 = *(const uint*)(relb + (p3 >> 16) * FEAT + lane * 2);
        uint xv4 = *(const uint*)(A + (p4 & 0xFFFF) * 256 + FEAT + lane * 2);
        uint rv4 = *(const uint*)(relb + (p4 >> 16) * FEAT + lane * 2);
        uint xv5 = *(const uint*)(A + (p5 & 0xFFFF) * 256 + FEAT + lane * 2);
        uint rv5 = *(const uint*)(relb + (p5 >> 16) * FEAT + lane * 2);
        uint xv6 = *(const uint*)(A + (p6 & 0xFFFF) * 256 + FEAT + lane * 2);
        uint rv6 = *(const uint*)(relb + (p6 >> 16) * FEAT + lane * 2);
        uint xv7 = *(const uint*)(A + (p7 & 0xFFFF) * 256 + FEAT + lane * 2);
        uint rv7 = *(const uint*)(relb + (p7 >> 16) * FEAT + lane * 2);
        ax += bflo(xv0) + bflo(rv0) + bflo(xv1) + bflo(rv1)
            + bflo(xv2) + bflo(rv2) + bflo(xv3) + bflo(rv3)
            + bflo(xv4) + bflo(rv4) + bflo(xv5) + bflo(rv5)
            + bflo(xv6) + bflo(rv6) + bflo(xv7) + bflo(rv7);
        ay += bfhi(xv0) + bfhi(rv0) + bfhi(xv1) + bfhi(rv1)
            + bfhi(xv2) + bfhi(rv2) + bfhi(xv3) + bfhi(rv3)
            + bfhi(xv4) + bfhi(rv4) + bfhi(xv5) + bfhi(rv5)
            + bfhi(xv6) + bfhi(rv6) + bfhi(xv7) + bfhi(rv7);
    }
    for (; e + 4 <= e1; e += 4) {
        int p0 = packed[e], p1 = packed[e + 1], p2 = packed[e + 2], p3 = packed[e + 3];
        uint xv0 = *(const uint*)(A + (p0 & 0xFFFF) * 256 + FEAT + lane * 2);
        uint rv0 = *(const uint*)(relb + (p0 >> 16) * FEAT + lane * 2);
        uint xv1 = *(const uint*)(A + (p1 & 0xFFFF) * 256 + FEAT + lane * 2);
        uint rv1 = *(const uint*)(relb + (p1 >> 16) * FEAT + lane * 2);
        uint xv2 = *(const uint*)(A + (p2 & 0xFFFF) * 256 + FEAT + lane * 2);
        uint rv2 = *(const uint*)(relb + (p2 >> 16) * FEAT + lane * 2);
        uint xv3 = *(const uint*)(A + (p3 & 0xFFFF) * 256 + FEAT + lane * 2);
        uint rv3 = *(const uint*)(relb + (p3 >> 16) * FEAT + lane * 2);
        ax += bflo(xv0) + bflo(rv0) + bflo(xv1) + bflo(rv1)
            + bflo(xv2) + bflo(rv2) + bflo(xv3) + bflo(rv3);
        ay += bfhi(xv0) + bfhi(rv0) + bfhi(xv1) + bfhi(rv1)
            + bfhi(xv2) + bfhi(rv2) + bfhi(xv3) + bfhi(rv3);
    }
    for (; e + 2 <= e1; e += 2) {
        int p0 = packed[e], p1 = packed[e + 1];
        uint xv0 = *(const uint*)(A + (p0 & 0xFFFF) * 256 + FEAT + lane * 2);
        uint rv0 = *(const uint*)(relb + (p0 >> 16) * FEAT + lane * 2);
        uint xv1 = *(const uint*)(A + (p1 & 0xFFFF) * 256 + FEAT + lane * 2);
        uint rv1 = *(const uint*)(relb + (p1 >> 16) * FEAT + lane * 2);
        ax += bflo(xv0) + bflo(rv0) + bflo(xv1) + bflo(rv1);
        ay += bfhi(xv0) + bfhi(rv0) + bfhi(xv1) + bfhi(rv1);
    }
    if (e < e1) {
        int p = packed[e];
        uint xv = *(const uint*)(A + (p & 0xFFFF) * 256 + FEAT + lane * 2);
        uint rv = *(const uint*)(relb + (p >> 16) * FEAT + lane * 2);
        ax += bflo(xv) + bflo(rv);
        ay += bfhi(xv) + bfhi(rv);
    }
    float invd = 1.0f / fmaxf((float)(e1 - e0), 1.0f);
    uint o = (uint)f2bf(ax * invd) | ((uint)f2bf(ay * invd) << 16);
    *(uint*)(A + node * 256 + lane * 2) = o;
}

// ---- hy: TM=32, fragment-major B, 16KB LDS (r19/r20 version).
__global__ __launch_bounds__(256) void k_hy(
    const ushort* __restrict__ A, const ushort* __restrict__ Wt1,
    const ushort* __restrict__ W1t,
    const float* __restrict__ bm, const float* __restrict__ b1,
    ushort* __restrict__ y, float* __restrict__ pb)
{
    __shared__ ushort a_s[32 * 256];      // 16 KB
    int tid = threadIdx.x;
    int w = tid >> 6, l = tid & 63;
    int lr = l & 15, lk = l >> 4;
    int m0 = blockIdx.x * 32;

    {
        const ushort* srcb = A + (size_t)m0 * 256;
        #pragma unroll
        for (int j = 0; j < 4; ++j) {
            int slot = (w * 4 + j) * 64 + l;
            int lrow = slot >> 5, lgr = slot & 31;
            GLL(srcb + lrow * 256 + ((lgr ^ (lrow & 7)) << 3), &a_s[(w * 4 + j) * 512]);
        }
    }
    __syncthreads();

    f32x4 acc[2][4] = {};
    const ushort* Bp = Wt1 + w * 16384 + l * 8;
    #pragma unroll
    for (int kk = 0; kk < 8; ++kk) {
        bf16x8 a[2], b[4];
        #pragma unroll
        for (int mb = 0; mb < 2; ++mb) {
            int row = mb * 16 + lr;
            a[mb] = *(const bf16x8*)&a_s[row * 256 + (((kk * 4 + lk) ^ (lr & 7)) << 3)];
        }
        #pragma unroll
        for (int nb = 0; nb < 4; ++nb) b[nb] = *(const bf16x8*)(Bp + kk * 2048 + nb * 512);
        #pragma unroll
        for (int mb = 0; mb < 2; ++mb)
            #pragma unroll
            for (int nb = 0; nb < 4; ++nb)
                acc[mb][nb] = MFMA(a[mb], b[nb], acc[mb][nb]);
    }
    __syncthreads();

    #pragma unroll
    for (int nb = 0; nb < 4; ++nb) {
        int col = w * 64 + nb * 16 + lr;
        float bias = bm[col];
        #pragma unroll
        for (int mb = 0; mb < 2; ++mb)
            #pragma unroll
            for (int r = 0; r < 4; ++r) {
                int row = mb * 16 + lk * 4 + r;
                a_s[row * 256 + (col ^ ((row & 7) << 3))] = f2bf(acc[mb][nb][r] + bias);
            }
    }
    __syncthreads();

    f32x4 acc2[2][4] = {};
    const ushort* B2p = W1t + w * 16384 + l * 8;
    #pragma unroll
    for (int kk = 0; kk < 8; ++kk) {
        bf16x8 a[2], b[4];
        #pragma unroll
        for (int mb = 0; mb < 2; ++mb) {
            int row = mb * 16 + lr;
            a[mb] = *(const bf16x8*)&a_s[row * 256 + ((kk * 32 + lk * 8) ^ ((row & 7) << 3))];
        }
        #pragma unroll
        for (int nb = 0; nb < 4; ++nb) b[nb] = *(const bf16x8*)(B2p + kk * 2048 + nb * 512);
        #pragma unroll
        for (int mb = 0; mb < 2; ++mb)
            #pragma unroll
            for (int nb = 0; nb < 4; ++nb)
                acc2[mb][nb] = MFMA(a[mb], b[nb], acc2[mb][nb]);
    }
    __syncthreads();

    #pragma unroll
    for (int nb = 0; nb < 4; ++nb) {
        int col = w * 64 + nb * 16 + lr;
        float b1v = b1[col];
        float cs = 0.f, cq = 0.f;
        #pragma unroll
        for (int mb = 0; mb < 2; ++mb)
            #pragma unroll
            for (int r = 0; r < 4; ++r) {
                int row = mb * 16 + lk * 4 + r;
                float v = acc2[mb][nb][r] + b1v;
                if (m0 + row < N_ENT) { cs += v; cq += v * v; }
                a_s[row * 256 + (col ^ ((row & 7) << 3))] = f2bf(v);
            }
        cs += __shfl_xor(cs, 16); cs += __shfl_xor(cs, 32);
        cq += __shfl_xor(cq, 16); cq += __shfl_xor(cq, 32);
        if (lk == 0) {
            *(float2*)(pb + (size_t)blockIdx.x * 512 + col * 2) = make_float2(cs, cq);
        }
    }
    __syncthreads();
    ushort* yp = y + (size_t)m0 * 256;
    #pragma unroll
    for (int i = 0; i < 4; ++i) {
        int off = i * 2048 + tid * 8;
        *(uint4*)(yp + off) = *(const uint4*)&a_s[off];
    }
}

// ---- red1: 196 blocks x 8 tiles -> pb2
__global__ __launch_bounds__(256) void k_red1(
    const float* __restrict__ pb, float* __restrict__ pb2)
{
    int b = blockIdx.x, tid = threadIdx.x;
    int t0 = b * 8;
    float sx = 0.f, sy = 0.f;
    #pragma unroll
    for (int i = 0; i < 8; ++i) {
        int t = t0 + i;
        if (t < NT32) {
            float2 v = *(const float2*)(pb + (size_t)t * 512 + tid * 2);
            sx += v.x; sy += v.y;
        }
    }
    *(float2*)(pb2 + (size_t)b * 512 + tid * 2) = make_float2(sx, sy);
}

// ---- red2: stage-2 reduce + BN finalize
__global__ __launch_bounds__(256) void k_red2(
    const float* __restrict__ pb2,
    const float* __restrict__ gamma, const float* __restrict__ beta,
    float* __restrict__ scale, float* __restrict__ shift)
{
    int c = threadIdx.x;
    float s = 0.f, q = 0.f;
    int b = 0;
    #pragma unroll
    for (; b + 8 <= RED_BLKS; b += 8) {
        float2 v0 = *(const float2*)(pb2 + (size_t)(b + 0) * 512 + c * 2);
        float2 v1 = *(const float2*)(pb2 + (size_t)(b + 1) * 512 + c * 2);
        float2 v2 = *(const float2*)(pb2 + (size_t)(b + 2) * 512 + c * 2);
        float2 v3 = *(const float2*)(pb2 + (size_t)(b + 3) * 512 + c * 2);
        float2 v4 = *(const float2*)(pb2 + (size_t)(b + 4) * 512 + c * 2);
        float2 v5 = *(const float2*)(pb2 + (size_t)(b + 5) * 512 + c * 2);
        float2 v6 = *(const float2*)(pb2 + (size_t)(b + 6) * 512 + c * 2);
        float2 v7 = *(const float2*)(pb2 + (size_t)(b + 7) * 512 + c * 2);
        s += v0.x + v1.x + v2.x + v3.x + v4.x + v5.x + v6.x + v7.x;
        q += v0.y + v1.y + v2.y + v3.y + v4.y + v5.y + v6.y + v7.y;
    }
    for (; b < RED_BLKS; ++b) {
        float2 v = *(const float2*)(pb2 + (size_t)b * 512 + c * 2);
        s += v.x; q += v.y;
    }
    const float invn = 1.0f / (float)N_ENT;
    float mean = s * invn;
    float var  = q * invn - mean * mean;
    float rstd = rsqrtf(var + BN_EPS);
    float sc   = gamma[c] * rstd;
    scale[c] = sc;
    shift[c] = beta[c] - mean * sc;
}

// ---- zout: TM=32, fragment-major B (r20 version).
__global__ __launch_bounds__(256) void k_zout(
    const ushort* __restrict__ y, const float* __restrict__ scale,
    const float* __restrict__ shift, const ushort* __restrict__ W2t,
    const float* __restrict__ b2, float* __restrict__ out)
{
    __shared__ ushort z_s[32 * 256];      // 16 KB
    int tid = threadIdx.x;
    int w = tid >> 6, l = tid & 63;
    int lr = l & 15, lk = l >> 4;
    int m0 = blockIdx.x * 32;

    {
        const ushort* srcb = y + (size_t)m0 * 256;
        #pragma unroll
        for (int j = 0; j < 4; ++j)
            GLL(srcb + ((w * 4 + j) * 64 + l) * 8, &z_s[(w * 4 + j) * 512]);
    }
    __syncthreads();

    f32x4 acc[2][2] = {};
    const ushort* Bp = W2t + w * 8192 + l * 8;
    #pragma unroll
    for (int kk = 0; kk < 8; ++kk) {
        int kb = kk * 32 + lk * 8;
        float scv[8], shv[8];
        *(float4*)&scv[0] = *(const float4*)(scale + kb);
        *(float4*)&scv[4] = *(const float4*)(scale + kb + 4);
        *(float4*)&shv[0] = *(const float4*)(shift + kb);
        *(float4*)&shv[4] = *(const float4*)(shift + kb + 4);
        bf16x8 b[2];
        #pragma unroll
        for (int nb = 0; nb < 2; ++nb) b[nb] = *(const bf16x8*)(Bp + kk * 1024 + nb * 512);
        bf16x8 a[2];
        #pragma unroll
        for (int mb = 0; mb < 2; ++mb) {
            int row = mb * 16 + lr;
            uint4 uv = *(const uint4*)&z_s[row * 256 + (kb ^ ((row & 7) << 3))];
            uint wd[4] = {uv.x, uv.y, uv.z, uv.w};
            #pragma unroll
            for (int j = 0; j < 8; ++j) {
                uint bits = (j & 1) ? (wd[j >> 1] & 0xFFFF0000u) : (wd[j >> 1] << 16);
                float f = __uint_as_float(bits);
                float z = fmaxf(f * scv[j] + shv[j], 0.f);
                a[mb][j] = (short)f2bf(z);
            }
        }
        #pragma unroll
        for (int mb = 0; mb < 2; ++mb)
            #pragma unroll
            for (int nb = 0; nb < 2; ++nb)
                acc[mb][nb] = MFMA(a[mb], b[nb], acc[mb][nb]);
    }
    #pragma unroll
    for (int nb = 0; nb < 2; ++nb) {
        int col = w * 32 + nb * 16 + lr;
        float b2v = b2[col];
        #pragma unroll
        for (int mb = 0; mb < 2; ++mb)
            #pragma unroll
            for (int r = 0; r < 4; ++r) {
                int row = m0 + mb * 16 + lk * 4 + r;
                if (row < N_ENT) out[row * OUT_D + col] = acc[mb][nb][r] + b2v;
            }
    }
}

extern "C" void kernel_launch(void* const* d_in, const int* in_sizes, int n_in,
                              void* d_out, int out_size, void* d_ws, size_t ws_size,
                              hipStream_t stream)
{
    const int*   ei    = (const int*)d_in[0];
    const int*   et    = (const int*)d_in[1];
    const float* x     = (const float*)d_in[2];
    const float* rel   = (const float*)d_in[3];
    const float* Wm    = (const float*)d_in[4];
    const float* bm    = (const float*)d_in[5];
    const float* Wsf   = (const float*)d_in[6];
    const float* W1    = (const float*)d_in[7];
    const float* b1    = (const float*)d_in[8];
    const float* gamma = (const float*)d_in[9];
    const float* beta  = (const float*)d_in[10];
    const float* W2    = (const float*)d_in[11];
    const float* b2    = (const float*)d_in[12];
    float* out = (float*)d_out;

    char* ws = (char*)d_ws;
    float*  scale  = (float*)(ws + OFF_SCALE);
    float*  shift  = (float*)(ws + OFF_SHIFT);
    ushort* relb   = (ushort*)(ws + OFF_RELB);
    ushort* Wt1    = (ushort*)(ws + OFF_WT1);
    ushort* W1t    = (ushort*)(ws + OFF_W1T);
    ushort* W2t    = (ushort*)(ws + OFF_W2T);
    ushort* A      = (ushort*)(ws + OFF_A);
    ushort* y      = (ushort*)(ws + OFF_Y);
    float*  pb     = (float*)(ws + OFF_PB);
    float*  pb2    = (float*)(ws + OFF_PB2);
    int*    rowptr = (int*)(ws + OFF_ROWPTR);
    int*    packed = (int*)(ws + OFF_PACKED);
    int*    ebuf   = (int*)(ws + OFF_EBUF);
    int*    chist  = (int*)(ws + OFF_CHIST);
    int*    offa   = (int*)(ws + OFF_OFFA);
    int*    cbase  = (int*)(ws + OFF_CBASE);

    k_prep <<<3816, 256, 0, stream>>>(x, Wm, Wsf, W1, W2, rel, A, Wt1, W1t, W2t, relb);
    k_chist<<<NBLK_E, 256, 0, stream>>>(ei, chist);
    k_cscan<<<1, 256, 0, stream>>>(chist, offa, cbase);
    k_cscat<<<NBLK_E, 256, 0, stream>>>(ei, et, offa, cbase, ebuf);
    k_fine <<<NBUCK, 256, 0, stream>>>(ebuf, cbase, rowptr, packed);
    k_agg  <<<N_ENT / 4, 256, 0, stream>>>(rowptr, packed, A, relb);
    k_hy   <<<NT32, 256, 0, stream>>>(A, Wt1, W1t, bm, b1, y, pb);
    k_red1 <<<RED_BLKS, 256, 0, stream>>>(pb, pb2);
    k_red2 <<<1, 256, 0, stream>>>(pb2, gamma, beta, scale, shift);
    k_zout <<<NT32, 256, 0, stream>>>(y, scale, shift, W2t, b2, out);
}

// Round 22
// 140.614 us; speedup vs baseline: 1.3489x; 1.0739x over previous
//
#include <hip/hip_runtime.h>
#include <hip/hip_bf16.h>

#define N_ENT   50000
#define N_EDGE  600000
#define FEAT    128
#define HID     256
#define OUT_D   128
#define MROWS   50048        // N_ENT padded to 64
#define BN_EPS  1e-5f
#define NT32    (MROWS / 32) // 1564 row-tiles of 32
#define RED_BLKS 196         // ceil(NT32/8)
#define NBUCK   196          // coarse buckets (dst >> 8)
#define NBLK_E  147          // ceil(N_EDGE / 4096)

// ---------------- ws layout (bytes) ----------------
#define OFF_SCALE   202048          // [HID] f32
#define OFF_SHIFT   203072          // [HID] f32
#define OFF_RELB    204096          // [101][128] bf16
#define OFF_WT1     229952          // fragment-major packed WmWsf^T  131,072
#define OFF_W1T     361024          // fragment-major packed W1^T     131,072
#define OFF_W2T     492096          // fragment-major packed W2^T     65,536
#define OFF_A       557632          // [MROWS][256] bf16 ([agg|x], linear)
#define OFF_Y       26182208        // [MROWS][256] bf16 (swizzled granules)
#define OFF_PB      52000000        // [NT32][512] f32 partials
#define OFF_PB2     55210000        // [196][512] f32 stage-2 partials
#define OFF_ROWPTR  56000000        // [N_ENT+1] i32
#define OFF_PACKED  56400064        // [N_EDGE] i32 (src | type<<16), dst-sorted
#define OFF_EBUF    58900000        // [N_EDGE] i32 coarse-bucketed
#define OFF_CHIST   61300000        // [NBLK_E][NBUCK] i32
#define OFF_CBASE   61540000        // [NBUCK+1] i32

typedef __attribute__((ext_vector_type(8))) short bf16x8;
typedef __attribute__((ext_vector_type(4))) float f32x4;

#define GLL(gp, lp) __builtin_amdgcn_global_load_lds( \
    (const __attribute__((address_space(1))) void*)(gp), \
    (__attribute__((address_space(3))) void*)(lp), 16, 0, 0)

#define MFMA(a, b, c) __builtin_amdgcn_mfma_f32_16x16x32_bf16((a), (b), (c), 0, 0, 0)

__device__ __forceinline__ ushort f2bf(float f) {
    uint u = __float_as_uint(f);
    return (ushort)((u + 0x7FFFu + ((u >> 16) & 1u)) >> 16);
}
__device__ __forceinline__ float bflo(uint u) { return __uint_as_float(u << 16); }
__device__ __forceinline__ float bfhi(uint u) { return __uint_as_float(u & 0xFFFF0000u); }

// ---- prep (fused): coarse histogram | cvt x->A right half | weight pack
// chist blocks FIRST so the sort chain's input is ready earliest.
__global__ __launch_bounds__(256) void k_prep(
    const float* __restrict__ x, const int* __restrict__ ei,
    const float* __restrict__ Wm, const float* __restrict__ Wsf,
    const float* __restrict__ W1, const float* __restrict__ W2,
    const float* __restrict__ rel,
    ushort* __restrict__ A, int* __restrict__ chist,
    ushort* __restrict__ Wt1, ushort* __restrict__ W1t,
    ushort* __restrict__ W2t, ushort* __restrict__ relb)
{
    int b = blockIdx.x;
    int t = threadIdx.x;
    if (b < NBLK_E) {                          // coarse histogram (LDS atomics)
        __shared__ int h[NBUCK];
        if (t < NBUCK) h[t] = 0;
        __syncthreads();
        #pragma unroll
        for (int r = 0; r < 16; ++r) {
            int e = (b * 16 + r) * 256 + t;
            if (e < N_EDGE) atomicAdd(&h[ei[N_EDGE + e] >> 8], 1);
        }
        __syncthreads();
        if (t < NBUCK) chist[b * NBUCK + t] = h[t];
    } else if (b < NBLK_E + 3125) {
        int idx = (b - NBLK_E) * 256 + t;      // 800,000 exactly
        int m = idx >> 4;
        int c = (idx & 15) * 8;
        float4 f0 = *(const float4*)(x + m * FEAT + c);
        float4 f1 = *(const float4*)(x + m * FEAT + c + 4);
        uint4 o;
        o.x = (uint)f2bf(f0.x) | ((uint)f2bf(f0.y) << 16);
        o.y = (uint)f2bf(f0.z) | ((uint)f2bf(f0.w) << 16);
        o.z = (uint)f2bf(f1.x) | ((uint)f2bf(f1.y) << 16);
        o.w = (uint)f2bf(f1.z) | ((uint)f2bf(f1.w) << 16);
        *(uint4*)(A + m * 256 + FEAT + c) = o;
    } else {
        int idx = (b - NBLK_E - 3125) * 256 + t;
        if (idx < 65536) {                 // Wt1 pack
            int n = idx >> 8, k = idx & 255;
            float v = (k < FEAT) ? Wm[k * HID + n] : Wsf[(k - FEAT) * HID + n];
            int w = n >> 6, nb = (n >> 4) & 3, lr = n & 15;
            int kk = k >> 5, lk = (k >> 3) & 3, j = k & 7;
            int l = lk * 16 + lr;
            Wt1[(((w * 8 + kk) * 4 + nb) * 64 + l) * 8 + j] = f2bf(v);
        } else if (idx < 131072) {         // W1t pack
            int o = idx - 65536;
            int n = o >> 8, k = o & 255;
            float v = W1[k * HID + n];
            int w = n >> 6, nb = (n >> 4) & 3, lr = n & 15;
            int kk = k >> 5, lk = (k >> 3) & 3, j = k & 7;
            int l = lk * 16 + lr;
            W1t[(((w * 8 + kk) * 4 + nb) * 64 + l) * 8 + j] = f2bf(v);
        } else if (idx < 163840) {         // W2t pack
            int o = idx - 131072;
            int n = o >> 8, k = o & 255;
            float v = W2[k * OUT_D + n];
            int w = n >> 5, nb = (n >> 4) & 1, lr = n & 15;
            int kk = k >> 5, lk = (k >> 3) & 3, j = k & 7;
            int l = lk * 16 + lr;
            W2t[(((w * 8 + kk) * 2 + nb) * 64 + l) * 8 + j] = f2bf(v);
        } else if (idx < 163840 + 101 * 128) {
            int o = idx - 163840;
            relb[o] = f2bf(rel[o]);
        }
    }
}

// ---- cscat (cscan folded): each block self-computes its bucket offsets
// from chist (147 coalesced column-sum iters, concurrent across blocks);
// block 0 also publishes cbase for k_fine.
__global__ __launch_bounds__(256) void k_cscat(
    const int* __restrict__ ei, const int* __restrict__ et,
    const int* __restrict__ chist,
    int* __restrict__ cbase, int* __restrict__ ebuf)
{
    __shared__ int base[NBUCK];
    __shared__ int sc[256];
    int t = threadIdx.x;
    int myoff = 0, total = 0;
    if (t < NBUCK) {
        #pragma unroll 4
        for (int b = 0; b < NBLK_E; ++b) {
            int c = chist[b * NBUCK + t];
            if (b < blockIdx.x) myoff += c;
            total += c;
        }
    }
    sc[t] = (t < NBUCK) ? total : 0;
    __syncthreads();
    for (int off = 1; off < 256; off <<= 1) {
        int u = (t >= off) ? sc[t - off] : 0;
        __syncthreads();
        sc[t] += u;
        __syncthreads();
    }
    int cb_ex = sc[t] - total;                 // exclusive bucket base
    if (t < NBUCK) base[t] = cb_ex + myoff;
    if (blockIdx.x == 0 && t < NBUCK) {
        cbase[t] = cb_ex;
        if (t == NBUCK - 1) cbase[NBUCK] = sc[t];
    }
    __syncthreads();
    #pragma unroll
    for (int r = 0; r < 16; ++r) {
        int e = (blockIdx.x * 16 + r) * 256 + t;
        if (e < N_EDGE) {
            int dst = ei[N_EDGE + e];
            int k = dst >> 8;
            int pos = atomicAdd(&base[k], 1);
            ebuf[pos] = ei[e] | (et[e] << 16) | ((dst & 255) << 23);
        }
    }
}

// ---- fine: per-bucket count + scan -> rowptr; rank-scatter -> packed (sorted)
__global__ __launch_bounds__(256) void k_fine(
    const int* __restrict__ ebuf, const int* __restrict__ cbase,
    int* __restrict__ rowptr, int* __restrict__ packed)
{
    __shared__ int cnt[256], sc[256];
    int t = threadIdx.x, b = blockIdx.x;
    int s0 = cbase[b], s1 = cbase[b + 1];
    cnt[t] = 0;
    __syncthreads();
    for (int e = s0 + t; e < s1; e += 256)
        atomicAdd(&cnt[(ebuf[e] >> 23) & 255], 1);
    __syncthreads();
    int v = cnt[t];
    sc[t] = v;
    __syncthreads();
    for (int off = 1; off < 256; off <<= 1) {
        int u = (t >= off) ? sc[t - off] : 0;
        __syncthreads();
        sc[t] += u;
        __syncthreads();
    }
    int ex = sc[t] - v;
    int node = b * 256 + t;
    if (node < N_ENT) rowptr[node] = s0 + ex;
    if (b == NBUCK - 1 && t == 0) rowptr[N_ENT] = s1;
    __syncthreads();
    cnt[t] = s0 + ex;           // running counters
    __syncthreads();
    for (int e = s0 + t; e < s1; e += 256) {
        int v32 = ebuf[e];
        int pos = atomicAdd(&cnt[(v32 >> 23) & 255], 1);
        packed[pos] = v32 & 0x7FFFFF;       // src | type<<16
    }
}

// ---- agg: segment mean, one node/wave; 8/4/2/1 MLP ladder
__global__ __launch_bounds__(256) void k_agg(
    const int* __restrict__ rowptr, const int* __restrict__ packed,
    ushort* __restrict__ A, const ushort* __restrict__ relb)
{
    int node = blockIdx.x * 4 + (threadIdx.x >> 6);
    int lane = threadIdx.x & 63;
    int e0 = rowptr[node], e1 = rowptr[node + 1];
    float ax = 0.f, ay = 0.f;
    int e = e0;
    for (; e + 8 <= e1; e += 8) {
        int p0 = packed[e],     p1 = packed[e + 1], p2 = packed[e + 2], p3 = packed[e + 3];
        int p4 = packed[e + 4], p5 = packed[e + 5], p6 = packed[e + 6], p7 = packed[e + 7];
        uint xv0 = *(const uint*)(A + (p0 & 0xFFFF) * 256 + FEAT + lane * 2);
        uint rv0 = *(const uint*)(relb + (p0 >> 16) * FEAT + lane * 2);
        uint xv1 = *(const uint*)(A + (p1 & 0xFFFF) * 256 + FEAT + lane * 2);
        uint rv1 = *(const uint*)(relb + (p1 >> 16) * FEAT + lane * 2);
        uint xv2 = *(const uint*)(A + (p2 & 0xFFFF) * 256 + FEAT + lane * 2);
        uint rv2 = *(const uint*)(relb + (p2 >> 16) * FEAT + lane * 2);
        uint xv3 = *(const uint*)(A + (p3 & 0xFFFF) * 256 + FEAT + lane * 2);
        uint rv3 = *(const uint*)(relb + (p3 >> 16) * FEAT + lane * 2);
        uint xv4 = *(const uint*)(A + (p4 & 0xFFFF) * 256 + FEAT + lane * 2);
        uint rv4 = *(const uint*)(relb + (p4 >> 16) * FEAT + lane * 2);
        uint xv5 = *(const uint*)(A + (p5 & 0xFFFF) * 256 + FEAT + lane * 2);
        uint rv5 = *(const uint*)(relb + (p5 >> 16) * FEAT + lane * 2);
        uint xv6 = *(const uint*)(A + (p6 & 0xFFFF) * 256 + FEAT + lane * 2);
        uint rv6 = *(const uint*)(relb + (p6 >> 16) * FEAT + lane * 2);
        uint xv7 = *(const uint*)(A + (p7 & 0xFFFF) * 256 + FEAT + lane * 2);
        uint rv7 = *(const uint*)(relb + (p7 >> 16) * FEAT + lane * 2);
        ax += bflo(xv0) + bflo(rv0) + bflo(xv1) + bflo(rv1)
            + bflo(xv2) + bflo(rv2) + bflo(xv3) + bflo(rv3)
            + bflo(xv4) + bflo(rv4) + bflo(xv5) + bflo(rv5)
            + bflo(xv6) + bflo(rv6) + bflo(xv7) + bflo(rv7);
        ay += bfhi(xv0) + bfhi(rv0) + bfhi(xv1) + bfhi(rv1)
            + bfhi(xv2) + bfhi(rv2) + bfhi(xv3) + bfhi(rv3)
            + bfhi(xv4) + bfhi(rv4) + bfhi(xv5) + bfhi(rv5)
            + bfhi(xv6) + bfhi(rv6) + bfhi(xv7) + bfhi(rv7);
    }
    for (; e + 4 <= e1; e += 4) {
        int p0 = packed[e], p1 = packed[e + 1], p2 = packed[e + 2], p3 = packed[e + 3];
        uint xv0 = *(const uint*)(A + (p0 & 0xFFFF) * 256 + FEAT + lane * 2);
        uint rv0 = *(const uint*)(relb + (p0 >> 16) * FEAT + lane * 2);
        uint xv1 = *(const uint*)(A + (p1 & 0xFFFF) * 256 + FEAT + lane * 2);
        uint rv1 = *(const uint*)(relb + (p1 >> 16) * FEAT + lane * 2);
        uint xv2 = *(const uint*)(A + (p2 & 0xFFFF) * 256 + FEAT + lane * 2);
        uint rv2 = *(const uint*)(relb + (p2 >> 16) * FEAT + lane * 2);
        uint xv3 = *(const uint*)(A + (p3 & 0xFFFF) * 256 + FEAT + lane * 2);
        uint rv3 = *(const uint*)(relb + (p3 >> 16) * FEAT + lane * 2);
        ax += bflo(xv0) + bflo(rv0) + bflo(xv1) + bflo(rv1)
            + bflo(xv2) + bflo(rv2) + bflo(xv3) + bflo(rv3);
        ay += bfhi(xv0) + bfhi(rv0) + bfhi(xv1) + bfhi(rv1)
            + bfhi(xv2) + bfhi(rv2) + bfhi(xv3) + bfhi(rv3);
    }
    for (; e + 2 <= e1; e += 2) {
        int p0 = packed[e], p1 = packed[e + 1];
        uint xv0 = *(const uint*)(A + (p0 & 0xFFFF) * 256 + FEAT + lane * 2);
        uint rv0 = *(const uint*)(relb + (p0 >> 16) * FEAT + lane * 2);
        uint xv1 = *(const uint*)(A + (p1 & 0xFFFF) * 256 + FEAT + lane * 2);
        uint rv1 = *(const uint*)(relb + (p1 >> 16) * FEAT + lane * 2);
        ax += bflo(xv0) + bflo(rv0) + bflo(xv1) + bflo(rv1);
        ay += bfhi(xv0) + bfhi(rv0) + bfhi(xv1) + bfhi(rv1);
    }
    if (e < e1) {
        int p = packed[e];
        uint xv = *(const uint*)(A + (p & 0xFFFF) * 256 + FEAT + lane * 2);
        uint rv = *(const uint*)(relb + (p >> 16) * FEAT + lane * 2);
        ax += bflo(xv) + bflo(rv);
        ay += bfhi(xv) + bfhi(rv);
    }
    float invd = 1.0f / fmaxf((float)(e1 - e0), 1.0f);
    uint o = (uint)f2bf(ax * invd) | ((uint)f2bf(ay * invd) << 16);
    *(uint*)(A + node * 256 + lane * 2) = o;
}

// ---- hy: TM=32, fragment-major B, 16KB LDS
__global__ __launch_bounds__(256) void k_hy(
    const ushort* __restrict__ A, const ushort* __restrict__ Wt1,
    const ushort* __restrict__ W1t,
    const float* __restrict__ bm, const float* __restrict__ b1,
    ushort* __restrict__ y, float* __restrict__ pb)
{
    __shared__ ushort a_s[32 * 256];      // 16 KB
    int tid = threadIdx.x;
    int w = tid >> 6, l = tid & 63;
    int lr = l & 15, lk = l >> 4;
    int m0 = blockIdx.x * 32;

    {
        const ushort* srcb = A + (size_t)m0 * 256;
        #pragma unroll
        for (int j = 0; j < 4; ++j) {
            int slot = (w * 4 + j) * 64 + l;
            int lrow = slot >> 5, lgr = slot & 31;
            GLL(srcb + lrow * 256 + ((lgr ^ (lrow & 7)) << 3), &a_s[(w * 4 + j) * 512]);
        }
    }
    __syncthreads();

    f32x4 acc[2][4] = {};
    const ushort* Bp = Wt1 + w * 16384 + l * 8;
    #pragma unroll
    for (int kk = 0; kk < 8; ++kk) {
        bf16x8 a[2], b[4];
        #pragma unroll
        for (int mb = 0; mb < 2; ++mb) {
            int row = mb * 16 + lr;
            a[mb] = *(const bf16x8*)&a_s[row * 256 + (((kk * 4 + lk) ^ (lr & 7)) << 3)];
        }
        #pragma unroll
        for (int nb = 0; nb < 4; ++nb) b[nb] = *(const bf16x8*)(Bp + kk * 2048 + nb * 512);
        #pragma unroll
        for (int mb = 0; mb < 2; ++mb)
            #pragma unroll
            for (int nb = 0; nb < 4; ++nb)
                acc[mb][nb] = MFMA(a[mb], b[nb], acc[mb][nb]);
    }
    __syncthreads();

    #pragma unroll
    for (int nb = 0; nb < 4; ++nb) {
        int col = w * 64 + nb * 16 + lr;
        float bias = bm[col];
        #pragma unroll
        for (int mb = 0; mb < 2; ++mb)
            #pragma unroll
            for (int r = 0; r < 4; ++r) {
                int row = mb * 16 + lk * 4 + r;
                a_s[row * 256 + (col ^ ((row & 7) << 3))] = f2bf(acc[mb][nb][r] + bias);
            }
    }
    __syncthreads();

    f32x4 acc2[2][4] = {};
    const ushort* B2p = W1t + w * 16384 + l * 8;
    #pragma unroll
    for (int kk = 0; kk < 8; ++kk) {
        bf16x8 a[2], b[4];
        #pragma unroll
        for (int mb = 0; mb < 2; ++mb) {
            int row = mb * 16 + lr;
            a[mb] = *(const bf16x8*)&a_s[row * 256 + ((kk * 32 + lk * 8) ^ ((row & 7) << 3))];
        }
        #pragma unroll
        for (int nb = 0; nb < 4; ++nb) b[nb] = *(const bf16x8*)(B2p + kk * 2048 + nb * 512);
        #pragma unroll
        for (int mb = 0; mb < 2; ++mb)
            #pragma unroll
            for (int nb = 0; nb < 4; ++nb)
                acc2[mb][nb] = MFMA(a[mb], b[nb], acc2[mb][nb]);
    }
    __syncthreads();

    #pragma unroll
    for (int nb = 0; nb < 4; ++nb) {
        int col = w * 64 + nb * 16 + lr;
        float b1v = b1[col];
        float cs = 0.f, cq = 0.f;
        #pragma unroll
        for (int mb = 0; mb < 2; ++mb)
            #pragma unroll
            for (int r = 0; r < 4; ++r) {
                int row = mb * 16 + lk * 4 + r;
                float v = acc2[mb][nb][r] + b1v;
                if (m0 + row < N_ENT) { cs += v; cq += v * v; }
                a_s[row * 256 + (col ^ ((row & 7) << 3))] = f2bf(v);
            }
        cs += __shfl_xor(cs, 16); cs += __shfl_xor(cs, 32);
        cq += __shfl_xor(cq, 16); cq += __shfl_xor(cq, 32);
        if (lk == 0) {
            *(float2*)(pb + (size_t)blockIdx.x * 512 + col * 2) = make_float2(cs, cq);
        }
    }
    __syncthreads();
    ushort* yp = y + (size_t)m0 * 256;
    #pragma unroll
    for (int i = 0; i < 4; ++i) {
        int off = i * 2048 + tid * 8;
        *(uint4*)(yp + off) = *(const uint4*)&a_s[off];
    }
}

// ---- red1: 196 blocks x 8 tiles -> pb2
__global__ __launch_bounds__(256) void k_red1(
    const float* __restrict__ pb, float* __restrict__ pb2)
{
    int b = blockIdx.x, tid = threadIdx.x;
    int t0 = b * 8;
    float sx = 0.f, sy = 0.f;
    #pragma unroll
    for (int i = 0; i < 8; ++i) {
        int t = t0 + i;
        if (t < NT32) {
            float2 v = *(const float2*)(pb + (size_t)t * 512 + tid * 2);
            sx += v.x; sy += v.y;
        }
    }
    *(float2*)(pb2 + (size_t)b * 512 + tid * 2) = make_float2(sx, sy);
}

// ---- red2: stage-2 reduce + BN finalize
__global__ __launch_bounds__(256) void k_red2(
    const float* __restrict__ pb2,
    const float* __restrict__ gamma, const float* __restrict__ beta,
    float* __restrict__ scale, float* __restrict__ shift)
{
    int c = threadIdx.x;
    float s = 0.f, q = 0.f;
    int b = 0;
    #pragma unroll
    for (; b + 8 <= RED_BLKS; b += 8) {
        float2 v0 = *(const float2*)(pb2 + (size_t)(b + 0) * 512 + c * 2);
        float2 v1 = *(const float2*)(pb2 + (size_t)(b + 1) * 512 + c * 2);
        float2 v2 = *(const float2*)(pb2 + (size_t)(b + 2) * 512 + c * 2);
        float2 v3 = *(const float2*)(pb2 + (size_t)(b + 3) * 512 + c * 2);
        float2 v4 = *(const float2*)(pb2 + (size_t)(b + 4) * 512 + c * 2);
        float2 v5 = *(const float2*)(pb2 + (size_t)(b + 5) * 512 + c * 2);
        float2 v6 = *(const float2*)(pb2 + (size_t)(b + 6) * 512 + c * 2);
        float2 v7 = *(const float2*)(pb2 + (size_t)(b + 7) * 512 + c * 2);
        s += v0.x + v1.x + v2.x + v3.x + v4.x + v5.x + v6.x + v7.x;
        q += v0.y + v1.y + v2.y + v3.y + v4.y + v5.y + v6.y + v7.y;
    }
    for (; b < RED_BLKS; ++b) {
        float2 v = *(const float2*)(pb2 + (size_t)b * 512 + c * 2);
        s += v.x; q += v.y;
    }
    const float invn = 1.0f / (float)N_ENT;
    float mean = s * invn;
    float var  = q * invn - mean * mean;
    float rstd = rsqrtf(var + BN_EPS);
    float sc   = gamma[c] * rstd;
    scale[c] = sc;
    shift[c] = beta[c] - mean * sc;
}

// ---- zout: TM=32, fragment-major B
__global__ __launch_bounds__(256) void k_zout(
    const ushort* __restrict__ y, const float* __restrict__ scale,
    const float* __restrict__ shift, const ushort* __restrict__ W2t,
    const float* __restrict__ b2, float* __restrict__ out)
{
    __shared__ ushort z_s[32 * 256];      // 16 KB
    int tid = threadIdx.x;
    int w = tid >> 6, l = tid & 63;
    int lr = l & 15, lk = l >> 4;
    int m0 = blockIdx.x * 32;

    {
        const ushort* srcb = y + (size_t)m0 * 256;
        #pragma unroll
        for (int j = 0; j < 4; ++j)
            GLL(srcb + ((w * 4 + j) * 64 + l) * 8, &z_s[(w * 4 + j) * 512]);
    }
    __syncthreads();

    f32x4 acc[2][2] = {};
    const ushort* Bp = W2t + w * 8192 + l * 8;
    #pragma unroll
    for (int kk = 0; kk < 8; ++kk) {
        int kb = kk * 32 + lk * 8;
        float scv[8], shv[8];
        *(float4*)&scv[0] = *(const float4*)(scale + kb);
        *(float4*)&scv[4] = *(const float4*)(scale + kb + 4);
        *(float4*)&shv[0] = *(const float4*)(shift + kb);
        *(float4*)&shv[4] = *(const float4*)(shift + kb + 4);
        bf16x8 b[2];
        #pragma unroll
        for (int nb = 0; nb < 2; ++nb) b[nb] = *(const bf16x8*)(Bp + kk * 1024 + nb * 512);
        bf16x8 a[2];
        #pragma unroll
        for (int mb = 0; mb < 2; ++mb) {
            int row = mb * 16 + lr;
            uint4 uv = *(const uint4*)&z_s[row * 256 + (kb ^ ((row & 7) << 3))];
            uint wd[4] = {uv.x, uv.y, uv.z, uv.w};
            #pragma unroll
            for (int j = 0; j < 8; ++j) {
                uint bits = (j & 1) ? (wd[j >> 1] & 0xFFFF0000u) : (wd[j >> 1] << 16);
                float f = __uint_as_float(bits);
                float z = fmaxf(f * scv[j] + shv[j], 0.f);
                a[mb][j] = (short)f2bf(z);
            }
        }
        #pragma unroll
        for (int mb = 0; mb < 2; ++mb)
            #pragma unroll
            for (int nb = 0; nb < 2; ++nb)
                acc[mb][nb] = MFMA(a[mb], b[nb], acc[mb][nb]);
    }
    #pragma unroll
    for (int nb = 0; nb < 2; ++nb) {
        int col = w * 32 + nb * 16 + lr;
        float b2v = b2[col];
        #pragma unroll
        for (int mb = 0; mb < 2; ++mb)
            #pragma unroll
            for (int r = 0; r < 4; ++r) {
                int row = m0 + mb * 16 + lk * 4 + r;
                if (row < N_ENT) out[row * OUT_D + col] = acc[mb][nb][r] + b2v;
            }
    }
}

extern "C" void kernel_launch(void* const* d_in, const int* in_sizes, int n_in,
                              void* d_out, int out_size, void* d_ws, size_t ws_size,
                              hipStream_t stream)
{
    const int*   ei    = (const int*)d_in[0];
    const int*   et    = (const int*)d_in[1];
    const float* x     = (const float*)d_in[2];
    const float* rel   = (const float*)d_in[3];
    const float* Wm    = (const float*)d_in[4];
    const float* bm    = (const float*)d_in[5];
    const float* Wsf   = (const float*)d_in[6];
    const float* W1    = (const float*)d_in[7];
    const float* b1    = (const float*)d_in[8];
    const float* gamma = (const float*)d_in[9];
    const float* beta  = (const float*)d_in[10];
    const float* W2    = (const float*)d_in[11];
    const float* b2    = (const float*)d_in[12];
    float* out = (float*)d_out;

    char* ws = (char*)d_ws;
    float*  scale  = (float*)(ws + OFF_SCALE);
    float*  shift  = (float*)(ws + OFF_SHIFT);
    ushort* relb   = (ushort*)(ws + OFF_RELB);
    ushort* Wt1    = (ushort*)(ws + OFF_WT1);
    ushort* W1t    = (ushort*)(ws + OFF_W1T);
    ushort* W2t    = (ushort*)(ws + OFF_W2T);
    ushort* A      = (ushort*)(ws + OFF_A);
    ushort* y      = (ushort*)(ws + OFF_Y);
    float*  pb     = (float*)(ws + OFF_PB);
    float*  pb2    = (float*)(ws + OFF_PB2);
    int*    rowptr = (int*)(ws + OFF_ROWPTR);
    int*    packed = (int*)(ws + OFF_PACKED);
    int*    ebuf   = (int*)(ws + OFF_EBUF);
    int*    chist  = (int*)(ws + OFF_CHIST);
    int*    cbase  = (int*)(ws + OFF_CBASE);

    k_prep <<<NBLK_E + 3125 + 691, 256, 0, stream>>>(x, ei, Wm, Wsf, W1, W2, rel,
                                                     A, chist, Wt1, W1t, W2t, relb);
    k_cscat<<<NBLK_E, 256, 0, stream>>>(ei, et, chist, cbase, ebuf);
    k_fine <<<NBUCK, 256, 0, stream>>>(ebuf, cbase, rowptr, packed);
    k_agg  <<<N_ENT / 4, 256, 0, stream>>>(rowptr, packed, A, relb);
    k_hy   <<<NT32, 256, 0, stream>>>(A, Wt1, W1t, bm, b1, y, pb);
    k_red1 <<<RED_BLKS, 256, 0, stream>>>(pb, pb2);
    k_red2 <<<1, 256, 0, stream>>>(pb2, gamma, beta, scale, shift);
    k_zout <<<NT32, 256, 0, stream>>>(y, scale, shift, W2t, b2, out);
}